// Round 7
// baseline (354.836 us; speedup 1.0000x reference)
//
#include <hip/hip_runtime.h>
#include <hip/hip_fp16.h>
#include <cstdint>
#include <cstddef>

#define N_NODES 40000
#define N_EDGES 640000
#define CH 128
#define NL 3
#define NB 64
#define LN_EPS 1e-5f
#define TSTRIDE 132  // tbuf row stride (floats): 16B-aligned, conflict-free
#define GBLK 625     // gemm blocks (N_NODES/64)
#define FBLK 2500    // fill blocks (N_EDGES/256)

typedef short short8 __attribute__((ext_vector_type(8)));
typedef float floatx4 __attribute__((ext_vector_type(4)));

__device__ __forceinline__ unsigned short bf16_rne(float f) {
    unsigned int u = __float_as_uint(f);
    unsigned int r = u + 0x7FFF + ((u >> 16) & 1);
    return (unsigned short)(r >> 16);
}

// ---------------------------------------------------------------- CSR build + W pack
// deg (2500 blocks) and pack (512 blocks) are independent -> one launch.
// W pack layout per matrix: [hi 16384 | lo 16384] bf16 shorts (64 KB).
// B-fragment layout for mfma_f32_16x16x32_bf16:
// frag[((kk*4+quad)*128 + n)*8 + j], k=kk*32+quad*8+j.
// bf16 split keeps lo NORMAL; fp16 split FAILED (R5/R6: lo subnormal, flushed).
__launch_bounds__(256)
__global__ void degpack_kernel(const int* __restrict__ ei, int* __restrict__ degi,
                               const float* __restrict__ pre_w, const float* __restrict__ conv_w,
                               const float* __restrict__ ffn_w1, const float* __restrict__ ffn_w2,
                               short* __restrict__ wpk) {
    int bid = blockIdx.x;
    if (bid < FBLK) {
        int e = bid * 256 + threadIdx.x;
        atomicAdd(&degi[ei[N_EDGES + e]], 1);
        return;
    }
    int idx = (bid - FBLK) * 256 + threadIdx.x;  // 8 * 16384 total
    int mat = idx >> 14;
    int e = idx & 16383;
    int k = e >> 7, n = e & 127;
    const float* src;
    switch (mat) {
        case 0: src = pre_w; break;
        case 1: case 2: case 3: src = conv_w + (size_t)(mat - 1) * 16384; break;
        case 4: case 5: src = ffn_w1 + (size_t)(mat - 4) * 16384; break;
        default: src = ffn_w2 + (size_t)(mat - 6) * 16384; break;
    }
    float f = src[e];
    unsigned short h = bf16_rne(f);
    float hf = __uint_as_float((unsigned)h << 16);
    unsigned short l = bf16_rne(f - hf);
    int kk = k >> 5, quad = (k >> 3) & 3, j = k & 7;
    int frag = ((kk * 4 + quad) * 128 + n) * 8 + j;
    wpk[(size_t)mat * 32768 + frag] = (short)h;
    wpk[(size_t)mat * 32768 + 16384 + frag] = (short)l;
}

// scan1 + isq fused
__global__ void scan1_kernel(const int* __restrict__ degi, int* __restrict__ rowptr,
                             int* __restrict__ bsum, float* __restrict__ isq) {
    __shared__ int s[256];
    int t = threadIdx.x;
    int i = blockIdx.x * 256 + t;
    int v = (i < N_NODES) ? degi[i] : 0;
    if (i < N_NODES) isq[i] = rsqrtf((float)v + 1.0f);
    s[t] = v;
    __syncthreads();
    for (int off = 1; off < 256; off <<= 1) {
        int add = (t >= off) ? s[t - off] : 0;
        __syncthreads();
        s[t] += add;
        __syncthreads();
    }
    if (i < N_NODES) rowptr[i + 1] = s[t];
    if (t == 255) bsum[blockIdx.x] = s[255];
}

// scan2+scan3 merged: every block redundantly scans the 157 block sums in LDS
// (~2 us, parallel across blocks) and applies its own exclusive offset.
__global__ void scan23_kernel(const int* __restrict__ bsum, int* __restrict__ rowptr, int nb) {
    __shared__ int s[256];
    int t = threadIdx.x;
    int v = (t < nb) ? bsum[t] : 0;
    s[t] = v;
    __syncthreads();
    for (int off = 1; off < 256; off <<= 1) {
        int add = (t >= off) ? s[t - off] : 0;
        __syncthreads();
        s[t] += add;
        __syncthreads();
    }
    int bid = blockIdx.x;
    int boff = (bid > 0) ? s[bid - 1] : 0;   // exclusive prefix of this block
    int i = bid * 256 + t;
    if (i < N_NODES) rowptr[i + 1] += boff;
    if (i == 0 && bid == 0) rowptr[0] = 0;
}

// ---------------------------------------------------------------- GEMM core
// R7 structure: 4 waves/block, wave (rh,ch) owns rows rh*32..+32 x cols
// ch*64..+64. Same per-block B-traffic as R3/R6 (32 fragment-loads/kk/block)
// but 2x the waves (2500, 2.44/SIMD) and half the per-wave serial chain
// (8 B-loads + 24 MFMAs per kk) -> latency hiding doubles. R6 counters:
// MfmaUtil 6%, Occupancy 17.6%, nothing saturated = pure latency bound at
// 1.22 waves/SIMD. Numerics: per-element MFMA sequence and hi/lo order
// unchanged; LN re-reads its 8 col values from tbuf in the SAME c-order and
// runs the SAME 16-lane butterfly -> bit-identical (R5/R8/R9: order pinned).

// Split an 8-float A sliver into bf16 hi/lo fragments.
__device__ __forceinline__ void split8(const float* av, short8& ahi, short8& alo) {
#pragma unroll
    for (int j = 0; j < 8; ++j) {
        unsigned short hb = bf16_rne(av[j]);
        ahi[j] = (short)hb;
        alo[j] = (short)bf16_rne(av[j] - __uint_as_float((unsigned)hb << 16));
    }
}

// 4 hi + 4 lo B-fragments (this wave's col-half) from L2-resident packed W.
__device__ __forceinline__ void loadB4(const short* __restrict__ wb, short8* bh, short8* bl) {
#pragma unroll
    for (int cc = 0; cc < 4; ++cc) {
        bh[cc] = *(const short8*)(wb + cc * 128);
        bl[cc] = *(const short8*)(wb + 16384 + cc * 128);
    }
}

// 24 MFMAs: 4 col-tiles x {hi*bhi, lo*bhi, hi*blo} x 2 row-tiles.
// Triplet order per output element identical to all prior rounds.
__device__ __forceinline__ void mfma24(const short8* bh, const short8* bl,
                                       short8 ah0, short8 al0, short8 ah1, short8 al1,
                                       floatx4* acc0, floatx4* acc1) {
#pragma unroll
    for (int cc = 0; cc < 4; ++cc) {
        acc0[cc] = __builtin_amdgcn_mfma_f32_16x16x32_bf16(ah0, bh[cc], acc0[cc], 0, 0, 0);
        acc0[cc] = __builtin_amdgcn_mfma_f32_16x16x32_bf16(al0, bh[cc], acc0[cc], 0, 0, 0);
        acc0[cc] = __builtin_amdgcn_mfma_f32_16x16x32_bf16(ah0, bl[cc], acc0[cc], 0, 0, 0);
        acc1[cc] = __builtin_amdgcn_mfma_f32_16x16x32_bf16(ah1, bh[cc], acc1[cc], 0, 0, 0);
        acc1[cc] = __builtin_amdgcn_mfma_f32_16x16x32_bf16(al1, bh[cc], acc1[cc], 0, 0, 0);
        acc1[cc] = __builtin_amdgcn_mfma_f32_16x16x32_bf16(ah1, bl[cc], acc1[cc], 0, 0, 0);
    }
}

// VARIANT 0 (pre+conv0):  T = A@W1+b1 -> tbuf and fp32 OutG(H); OutC = fp16(T@W2)
// VARIANT 1 (FFN+conv):   T = relu(A@W1+b1) -> tbuf;
//                         Hn = LN(T@W2+b2+Res) -> tbuf and fp32 OutG(H);
//                         OutC = fp16(Hn@W3)
template <int VARIANT>
__device__ __forceinline__ void gemm_core(int tid, int bid,
                                          const float* __restrict__ A, const short* __restrict__ W1pk,
                                          const float* __restrict__ b1, const short* __restrict__ W2pk,
                                          const float* __restrict__ b2, const float* __restrict__ Res,
                                          const float* __restrict__ gamma, const float* __restrict__ beta,
                                          const short* __restrict__ W3pk,
                                          float* __restrict__ OutG, __half* __restrict__ OutC) {
    __shared__ float tbuf[64 * TSTRIDE];    // 33 KB; full 128-col rows per block
    const int lane = tid & 63;
    const int wv = tid >> 6;                 // 0..3
    const int rh = wv >> 1;                  // row-half (32 rows)
    const int ch = wv & 1;                   // col-half (64 cols)
    const int row0 = bid * 64 + rh * 32;
    const int m = lane & 15;
    const int quad = lane >> 4;

    floatx4 acc[2][4];
#pragma unroll
    for (int t = 0; t < 2; ++t)
#pragma unroll
        for (int cc = 0; cc < 4; ++cc) acc[t][cc] = (floatx4){0.f, 0.f, 0.f, 0.f};

    const float* arow0 = A + (size_t)(row0 + m) * CH + quad * 8;
    const float* arow1 = arow0 + (size_t)16 * CH;
    float* trow_w = tbuf + (rh * 32) * TSTRIDE;                       // row base (this rh)
    const float* trow0 = tbuf + (rh * 32 + m) * TSTRIDE + quad * 8;   // A-frag reads
    const float* trow1 = trow0 + 16 * TSTRIDE;
    // per-lane B-fragment position: quad*1024 + m*8 + col-half*512; frag cc at +cc*128
    const int boff = quad * 1024 + m * 8 + ch * 512;

    // ---------------- GEMM 1: A @ W1 ----------------
#pragma unroll 1
    for (int kk = 0; kk < 4; ++kk) {
        float4 a0 = *(const float4*)(arow0 + kk * 32);
        float4 a1 = *(const float4*)(arow0 + kk * 32 + 4);
        float4 a2 = *(const float4*)(arow1 + kk * 32);
        float4 a3 = *(const float4*)(arow1 + kk * 32 + 4);
        float av0[8] = {a0.x, a0.y, a0.z, a0.w, a1.x, a1.y, a1.z, a1.w};
        float av1[8] = {a2.x, a2.y, a2.z, a2.w, a3.x, a3.y, a3.z, a3.w};
        short8 ahi0, alo0, ahi1, alo1;
        split8(av0, ahi0, alo0);
        split8(av1, ahi1, alo1);
        short8 bh[4], bl[4];
        loadB4(W1pk + kk * 4096 + boff, bh, bl);
        mfma24(bh, bl, ahi0, alo0, ahi1, alo1, acc[0], acc[1]);
    }

    // T epilogue -> tbuf (and H to global for VARIANT 0)
#pragma unroll
    for (int cc = 0; cc < 4; ++cc) {
        int col = (ch * 4 + cc) * 16 + m;
        float bv = b1[col];
#pragma unroll
        for (int t = 0; t < 2; ++t)
#pragma unroll
        for (int r = 0; r < 4; ++r) {
            int lrow = t * 16 + quad * 4 + r;
            float v = acc[t][cc][r] + bv;
            if (VARIANT == 1) v = fmaxf(v, 0.f);
            trow_w[lrow * TSTRIDE + col] = v;
            if (VARIANT == 0)
                OutG[(size_t)(row0 + lrow) * CH + col] = v;
        }
#pragma unroll
        for (int t = 0; t < 2; ++t) acc[t][cc] = (floatx4){0.f, 0.f, 0.f, 0.f};
    }
    __syncthreads();   // T complete (both col-halves) before GEMM2 A-reads

    // ---------------- GEMM 2: T @ W2 ----------------
#pragma unroll 1
    for (int kk = 0; kk < 4; ++kk) {
        float av0[8], av1[8];
#pragma unroll
        for (int j = 0; j < 8; ++j) av0[j] = trow0[kk * 32 + j];
#pragma unroll
        for (int j = 0; j < 8; ++j) av1[j] = trow1[kk * 32 + j];
        short8 ahi0, alo0, ahi1, alo1;
        split8(av0, ahi0, alo0);
        split8(av1, alo1, alo1);  // placeholder overwritten below
        split8(av1, ahi1, alo1);
        short8 bh[4], bl[4];
        loadB4(W2pk + kk * 4096 + boff, bh, bl);
        mfma24(bh, bl, ahi0, alo0, ahi1, alo1, acc[0], acc[1]);
    }

    if (VARIANT == 0) {
        // conv0 out: plain acc -> fp16 (conv bias applied in agg)
#pragma unroll
        for (int cc = 0; cc < 4; ++cc) {
            int col = (ch * 4 + cc) * 16 + m;
#pragma unroll
            for (int t = 0; t < 2; ++t)
#pragma unroll
            for (int r = 0; r < 4; ++r) {
                int row = row0 + t * 16 + quad * 4 + r;
                OutC[(size_t)row * CH + col] = __float2half(acc[t][cc][r]);
            }
        }
        return;
    }

    // ---------------- FFN epilogue: LN(acc + b2 + Res) ----------------
#pragma unroll
    for (int cc = 0; cc < 4; ++cc) {
        int col = (ch * 4 + cc) * 16 + m;
        float bv = b2[col];
#pragma unroll
        for (int t = 0; t < 2; ++t)
#pragma unroll
        for (int r = 0; r < 4; ++r)
            acc[t][cc][r] += bv + Res[(size_t)(row0 + t * 16 + quad * 4 + r) * CH + col];
    }
    // stage pre-LN values so every lane can re-read its row's full 128 cols
#pragma unroll
    for (int cc = 0; cc < 4; ++cc) {
        int col = (ch * 4 + cc) * 16 + m;
#pragma unroll
        for (int t = 0; t < 2; ++t)
#pragma unroll
        for (int r = 0; r < 4; ++r)
            trow_w[(t * 16 + quad * 4 + r) * TSTRIDE + col] = acc[t][cc][r];
    }
    __syncthreads();
    // row reduce: read the SAME 8 values in the SAME c-order as the pre-split
    // kernel's lane-local sum, then the SAME 16-lane butterfly -> bit-identical
    float mn[2][4], rs[2][4];
#pragma unroll
    for (int t = 0; t < 2; ++t)
#pragma unroll
    for (int r = 0; r < 4; ++r) {
        const float* rowp = trow_w + (t * 16 + quad * 4 + r) * TSTRIDE;
        float s = 0.f, q = 0.f;
#pragma unroll
        for (int c = 0; c < 8; ++c) {
            float v = rowp[c * 16 + m];
            s += v;
            q = fmaf(v, v, q);
        }
#pragma unroll
        for (int msk = 1; msk < 16; msk <<= 1) {
            s += __shfl_xor(s, msk);
            q += __shfl_xor(q, msk);
        }
        float mean = s * (1.f / CH);
        float var = q * (1.f / CH) - mean * mean;
        mn[t][r] = mean;
        rs[t][r] = rsqrtf(var + LN_EPS);
    }
    __syncthreads();   // all pre-LN reads done before overwriting with y
#pragma unroll
    for (int t = 0; t < 2; ++t)
#pragma unroll
    for (int r = 0; r < 4; ++r) {
        int lrow = t * 16 + quad * 4 + r;
        int row = row0 + lrow;
#pragma unroll
        for (int cc = 0; cc < 4; ++cc) {
            int col = (ch * 4 + cc) * 16 + m;
            float y = (acc[t][cc][r] - mn[t][r]) * rs[t][r] * gamma[col] + beta[col];
            OutG[(size_t)row * CH + col] = y;
            trow_w[lrow * TSTRIDE + col] = y;
        }
    }
#pragma unroll
    for (int t = 0; t < 2; ++t)
#pragma unroll
    for (int cc = 0; cc < 4; ++cc) acc[t][cc] = (floatx4){0.f, 0.f, 0.f, 0.f};
    __syncthreads();   // Hn complete before GEMM3 A-reads

    // ---------------- GEMM 3: Hn @ W3 (next layer's conv) ----------------
#pragma unroll 1
    for (int kk = 0; kk < 4; ++kk) {
        float av0[8], av1[8];
#pragma unroll
        for (int j = 0; j < 8; ++j) av0[j] = trow0[kk * 32 + j];
#pragma unroll
        for (int j = 0; j < 8; ++j) av1[j] = trow1[kk * 32 + j];
        short8 ahi0, alo0, ahi1, alo1;
        split8(av0, ahi0, alo0);
        split8(av1, ahi1, alo1);
        short8 bh[4], bl[4];
        loadB4(W3pk + kk * 4096 + boff, bh, bl);
        mfma24(bh, bl, ahi0, alo0, ahi1, alo1, acc[0], acc[1]);
    }

#pragma unroll
    for (int cc = 0; cc < 4; ++cc) {
        int col = (ch * 4 + cc) * 16 + m;
#pragma unroll
        for (int t = 0; t < 2; ++t)
#pragma unroll
        for (int r = 0; r < 4; ++r) {
            int row = row0 + t * 16 + quad * 4 + r;
            OutC[(size_t)row * CH + col] = __float2half(acc[t][cc][r]);
        }
    }
}

// variant-1 standalone kernel (FFN+conv triple-fusion)
template <int VARIANT>
__launch_bounds__(256)
__global__ void gemm_fused(const float* __restrict__ A, const short* __restrict__ W1pk,
                           const float* __restrict__ b1, const short* __restrict__ W2pk,
                           const float* __restrict__ b2, const float* __restrict__ Res,
                           const float* __restrict__ gamma, const float* __restrict__ beta,
                           const short* __restrict__ W3pk,
                           float* __restrict__ OutG, __half* __restrict__ OutC) {
    gemm_core<VARIANT>(threadIdx.x, blockIdx.x, A, W1pk, b1, W2pk, b2, Res,
                       gamma, beta, W3pk, OutG, OutC);
}

// Co-launch: blocks [0,GBLK) = variant-0 gemm (pre-scaler + conv0, 4 waves);
// blocks [GBLK,GBLK+FBLK) = fill_csr hiding under the gemm latency shadow
// (R6: fill added only ~5 us to the gemm0 dispatch).
__launch_bounds__(256)
__global__ void fillgemm0_kernel(const int* __restrict__ ei, const int* __restrict__ rowptr,
                                 int* __restrict__ fill, int* __restrict__ srcs,
                                 const float* __restrict__ A, const short* __restrict__ W1pk,
                                 const float* __restrict__ b1, const short* __restrict__ W2pk,
                                 float* __restrict__ OutG, __half* __restrict__ OutC) {
    int bid = blockIdx.x;
    if (bid < GBLK) {
        gemm_core<0>(threadIdx.x, bid, A, W1pk, b1, W2pk, nullptr, nullptr,
                     nullptr, nullptr, nullptr, OutG, OutC);
        return;
    }
    int e = (bid - GBLK) * 256 + threadIdx.x;
    int s = ei[e];
    int d = ei[N_EDGES + e];
    int pos = atomicAdd(&fill[d], 1);
    srcs[rowptr[d] + pos] = s;
}

// ---------------------------------------------------------------- aggregation
// One wave per dst node, HW fp16, out fp32. 8-deep manual load prefetch;
// fmas retired strictly in j-order (R5/R8/R9: reorder -> 7.3e-4 fail).
// FUSED=1: Hres = relu(LN(agg+bias)) + Hres.  FUSED=0: Out = agg+bias.
// (R15 lesson: do NOT fuse pooling via direct atomics.)
template <int FUSED>
__launch_bounds__(256)
__global__ void agg_kernel(const __half* __restrict__ HW, const int* __restrict__ rowptr,
                           const int* __restrict__ srcs, const float* __restrict__ isq,
                           const float* __restrict__ bias, const float* __restrict__ gamma,
                           const float* __restrict__ beta, float* __restrict__ Hres,
                           float* __restrict__ Out) {
    const int lane = threadIdx.x & 63;
    const int node = blockIdx.x * 4 + (threadIdx.x >> 6);
    const int start = rowptr[node];
    const int end = rowptr[node + 1];

    float ax = 0.f, ay = 0.f;
    for (int base = start; base < end; base += 64) {
        int idx = base + lane;
        int clamped = (idx < end) ? idx : (end - 1);
        int sl = srcs[clamped];
        float wl = isq[sl];
        int cnt = end - base;
        if (cnt > 64) cnt = 64;
        int j = 0;
        for (; j + 8 <= cnt; j += 8) {
            int s[8];
            float w[8];
            float2 v[8];
#pragma unroll
            for (int q = 0; q < 8; ++q) {
                s[q] = __shfl(sl, j + q);
                w[q] = __shfl(wl, j + q);
            }
#pragma unroll
            for (int q = 0; q < 8; ++q)
                v[q] = __half22float2(*(const __half2*)(HW + (size_t)s[q] * CH + lane * 2));
#pragma unroll
            for (int q = 0; q < 8; ++q) {
                ax = fmaf(w[q], v[q].x, ax);
                ay = fmaf(w[q], v[q].y, ay);
            }
        }
        for (; j + 4 <= cnt; j += 4) {
            int s0 = __shfl(sl, j), s1 = __shfl(sl, j + 1);
            int s2 = __shfl(sl, j + 2), s3 = __shfl(sl, j + 3);
            float w0 = __shfl(wl, j), w1 = __shfl(wl, j + 1);
            float w2 = __shfl(wl, j + 2), w3 = __shfl(wl, j + 3);
            float2 v0 = __half22float2(*(const __half2*)(HW + (size_t)s0 * CH + lane * 2));
            float2 v1 = __half22float2(*(const __half2*)(HW + (size_t)s1 * CH + lane * 2));
            float2 v2 = __half22float2(*(const __half2*)(HW + (size_t)s2 * CH + lane * 2));
            float2 v3 = __half22float2(*(const __half2*)(HW + (size_t)s3 * CH + lane * 2));
            ax = fmaf(w0, v0.x, ax); ay = fmaf(w0, v0.y, ay);
            ax = fmaf(w1, v1.x, ax); ay = fmaf(w1, v1.y, ay);
            ax = fmaf(w2, v2.x, ax); ay = fmaf(w2, v2.y, ay);
            ax = fmaf(w3, v3.x, ax); ay = fmaf(w3, v3.y, ay);
        }
        for (; j < cnt; ++j) {
            int s = __shfl(sl, j);
            float w = __shfl(wl, j);
            float2 vf = __half22float2(*(const __half2*)(HW + (size_t)s * CH + lane * 2));
            ax = fmaf(w, vf.x, ax);
            ay = fmaf(w, vf.y, ay);
        }
    }
    float d = isq[node];
    const __half2 hv = *(const __half2*)(HW + (size_t)node * CH + lane * 2);
    float2 hf = __half22float2(hv);
    const float2 bb = *(const float2*)(bias + lane * 2);
    float hx = d * ax + d * d * hf.x + bb.x;
    float hy = d * ay + d * d * hf.y + bb.y;

    if (!FUSED) {
        float2 o; o.x = hx; o.y = hy;
        *(float2*)(Out + (size_t)node * CH + lane * 2) = o;
        return;
    }
    float sum = hx + hy;
    float sq = hx * hx + hy * hy;
    for (int msk = 1; msk < 64; msk <<= 1) {
        sum += __shfl_xor(sum, msk);
        sq += __shfl_xor(sq, msk);
    }
    float mean = sum * (1.f / CH);
    float var = sq * (1.f / CH) - mean * mean;
    float rstd = rsqrtf(var + LN_EPS);
    const float2 gg = *(const float2*)(gamma + lane * 2);
    const float2 be = *(const float2*)(beta + lane * 2);
    float y0 = (hx - mean) * rstd * gg.x + be.x;
    float y1 = (hy - mean) * rstd * gg.y + be.y;
    float2* hp = (float2*)(Hres + (size_t)node * CH + lane * 2);
    float2 rr = *hp;
    float2 o;
    o.x = fmaxf(y0, 0.f) + rr.x;
    o.y = fmaxf(y1, 0.f) + rr.y;
    *hp = o;
}

// ---------------------------------------------------------------- pooling
__launch_bounds__(256)
__global__ void pool_kernel(const float* __restrict__ H, const int* __restrict__ batch,
                            float* __restrict__ g, float* __restrict__ cntf) {
    const int lane = threadIdx.x & 63;
    const int w = blockIdx.x * 4 + (threadIdx.x >> 6);
    const int n0 = w * 16;
    float lx = 0.f, ly = 0.f;
    int run = 0;
    int cur = batch[n0];
    for (int t = 0; t < 16; ++t) {
        int n = n0 + t;
        int b = batch[n];
        if (b != cur) {
            atomicAdd(&g[(size_t)cur * CH + lane * 2], lx);
            atomicAdd(&g[(size_t)cur * CH + lane * 2 + 1], ly);
            if (lane == 0) atomicAdd(&cntf[cur], (float)run);
            lx = ly = 0.f; run = 0; cur = b;
        }
        const float2 v = *(const float2*)(H + (size_t)n * CH + lane * 2);
        lx += v.x; ly += v.y; ++run;
    }
    atomicAdd(&g[(size_t)cur * CH + lane * 2], lx);
    atomicAdd(&g[(size_t)cur * CH + lane * 2 + 1], ly);
    if (lane == 0) atomicAdd(&cntf[cur], (float)run);
}

// ---------------------------------------------------------------- classifier
__launch_bounds__(128)
__global__ void cls_kernel(const float* __restrict__ g, const float* __restrict__ cntf,
                           const float* __restrict__ w1, const float* __restrict__ b1,
                           const float* __restrict__ w2, const float* __restrict__ b2,
                           float* __restrict__ out) {
    __shared__ float gm[CH];
    __shared__ float red[2];
    const int b = blockIdx.x;
    const int t = threadIdx.x;
    float inv = 1.f / fmaxf(cntf[b], 1.f);
    gm[t] = g[(size_t)b * CH + t] * inv;
    __syncthreads();
    float acc = b1[t];
    for (int k = 0; k < CH; ++k) acc = fmaf(gm[k], w1[(size_t)k * CH + t], acc);
    float v = fmaxf(acc, 0.f) * w2[t];
    for (int msk = 1; msk < 64; msk <<= 1) v += __shfl_xor(v, msk);
    if ((t & 63) == 0) red[t >> 6] = v;
    __syncthreads();
    if (t == 0) out[b] = red[0] + red[1] + b2[0];
}

// ---------------------------------------------------------------- launch

extern "C" void kernel_launch(void* const* d_in, const int* in_sizes, int n_in,
                              void* d_out, int out_size, void* d_ws, size_t ws_size,
                              hipStream_t stream) {
    const float* x      = (const float*)d_in[0];
    const int*   ei     = (const int*)d_in[1];
    const int*   batch  = (const int*)d_in[2];
    const float* pre_w  = (const float*)d_in[3];
    const float* pre_b  = (const float*)d_in[4];
    const float* conv_w = (const float*)d_in[5];
    const float* conv_b = (const float*)d_in[6];
    const float* ln_g   = (const float*)d_in[7];
    const float* ln_b   = (const float*)d_in[8];
    const float* ffn_w1 = (const float*)d_in[9];
    const float* ffn_b1 = (const float*)d_in[10];
    const float* ffn_w2 = (const float*)d_in[11];
    const float* ffn_b2 = (const float*)d_in[12];
    const float* fln_g  = (const float*)d_in[13];
    const float* fln_b  = (const float*)d_in[14];
    const float* cls_w1 = (const float*)d_in[15];
    const float* cls_b1 = (const float*)d_in[16];
    const float* cls_w2 = (const float*)d_in[17];
    const float* cls_b2 = (const float*)d_in[18];

    float* H    = (float*)d_ws;                       // 40000*128 f32 (residual)
    float* T    = H + (size_t)N_NODES * CH;           // f32 (final agg out)
    float* R    = T + (size_t)N_NODES * CH;           // scratch
    __half* HWh = (__half*)R;                         // conv out fp16 (alias)
    int*   degi = (int*)(R + (size_t)N_NODES * CH);
    int*   fill = degi + N_NODES;
    float* g    = (float*)(fill + N_NODES);           // zero zone contiguous
    float* cntf = g + (size_t)NB * CH;
    float* isq  = cntf + NB;
    int*  rowptr = (int*)(isq + N_NODES);
    int*  bsum   = rowptr + N_NODES + 1;
    int*  boff   = bsum + 256;
    int*  srcs   = boff + 256;
    short* wpk   = (short*)(srcs + N_EDGES);          // 8 x 32768 shorts

    const int nb_scan = (N_NODES + 255) / 256;  // 157

    hipMemsetAsync(degi, 0, (size_t)(2 * N_NODES + NB * CH + NB) * sizeof(int), stream);

    // deg (atomics) + W pack co-launched (independent)
    degpack_kernel<<<FBLK + 512, 256, 0, stream>>>(ei, degi, pre_w, conv_w,
                                                   ffn_w1, ffn_w2, wpk);
    scan1_kernel<<<nb_scan, 256, 0, stream>>>(degi, rowptr, bsum, isq);
    scan23_kernel<<<nb_scan, 256, 0, stream>>>(bsum, rowptr, nb_scan);
    // fill_csr + (pre-scaler + conv0 gemm) co-launched (independent)
    fillgemm0_kernel<<<GBLK + FBLK, 256, 0, stream>>>(ei, rowptr, fill, srcs,
                                                      x, wpk, pre_b,
                                                      wpk + 1 * 32768, H, HWh);

    const int lblk = N_NODES / 4;    // 10000

    for (int i = 0; i < NL; ++i) {
        if (i < NL - 1) {
            // H = relu(LN(agg(HWh)+conv_b)) + H   (fused)
            agg_kernel<1><<<lblk, 256, 0, stream>>>(HWh, rowptr, srcs, isq,
                                                    conv_b + (size_t)i * CH,
                                                    ln_g + (size_t)i * CH,
                                                    ln_b + (size_t)i * CH, H, nullptr);
            // H = LN(relu(H@w1+b1)@w2+b2+H); HWh = fp16(H@conv_w[i+1])  (triple-fused)
            gemm_fused<1><<<GBLK, 256, 0, stream>>>(H, wpk + (size_t)(4 + i) * 32768,
                                                    ffn_b1 + (size_t)i * CH,
                                                    wpk + (size_t)(6 + i) * 32768,
                                                    ffn_b2 + (size_t)i * CH, H,
                                                    fln_g + (size_t)i * CH,
                                                    fln_b + (size_t)i * CH,
                                                    wpk + (size_t)(2 + i) * 32768,
                                                    H, HWh);
        } else {
            // T = agg(HWh) + conv_b   (fp32)
            agg_kernel<0><<<lblk, 256, 0, stream>>>(HWh, rowptr, srcs, isq,
                                                    conv_b + (size_t)i * CH,
                                                    nullptr, nullptr, nullptr, T);
        }
    }

    pool_kernel<<<N_NODES / 64, 256, 0, stream>>>(T, batch, g, cntf);
    cls_kernel<<<NB, CH, 0, stream>>>(g, cntf, cls_w1, cls_b1, cls_w2, cls_b2,
                                      (float*)d_out);
}

// Round 8
// 341.992 us; speedup vs baseline: 1.0376x; 1.0376x over previous
//
#include <hip/hip_runtime.h>
#include <hip/hip_fp16.h>
#include <cstdint>
#include <cstddef>

#define N_NODES 40000
#define N_EDGES 640000
#define CH 128
#define NL 3
#define NB 64
#define LN_EPS 1e-5f
#define TSTRIDE 132   // tbuf row stride (floats): 16B-aligned, conflict-free
#define GBLK2 1250    // gemm blocks (N_NODES/32): 32 rows, 1 wave each
#define FBLK64 10000  // fill blocks (N_EDGES/64) in the co-launch
#define FBLK 2500     // deg blocks (N_EDGES/256)

typedef short short8 __attribute__((ext_vector_type(8)));
typedef float floatx4 __attribute__((ext_vector_type(4)));

__device__ __forceinline__ unsigned short bf16_rne(float f) {
    unsigned int u = __float_as_uint(f);
    unsigned int r = u + 0x7FFF + ((u >> 16) & 1);
    return (unsigned short)(r >> 16);
}

// ---------------------------------------------------------------- CSR build + W pack
// deg (2500 blocks) and pack (512 blocks) are independent -> one launch.
// W pack layout per matrix: [hi 16384 | lo 16384] bf16 shorts (64 KB).
// B-fragment layout for mfma_f32_16x16x32_bf16:
// frag[((kk*4+quad)*128 + n)*8 + j], k=kk*32+quad*8+j.
// bf16 split keeps lo NORMAL; fp16 split FAILED (R5/R6: lo subnormal, flushed).
__launch_bounds__(256)
__global__ void degpack_kernel(const int* __restrict__ ei, int* __restrict__ degi,
                               const float* __restrict__ pre_w, const float* __restrict__ conv_w,
                               const float* __restrict__ ffn_w1, const float* __restrict__ ffn_w2,
                               short* __restrict__ wpk) {
    int bid = blockIdx.x;
    if (bid < FBLK) {
        int e = bid * 256 + threadIdx.x;
        atomicAdd(&degi[ei[N_EDGES + e]], 1);
        return;
    }
    int idx = (bid - FBLK) * 256 + threadIdx.x;  // 8 * 16384 total
    int mat = idx >> 14;
    int e = idx & 16383;
    int k = e >> 7, n = e & 127;
    const float* src;
    switch (mat) {
        case 0: src = pre_w; break;
        case 1: case 2: case 3: src = conv_w + (size_t)(mat - 1) * 16384; break;
        case 4: case 5: src = ffn_w1 + (size_t)(mat - 4) * 16384; break;
        default: src = ffn_w2 + (size_t)(mat - 6) * 16384; break;
    }
    float f = src[e];
    unsigned short h = bf16_rne(f);
    float hf = __uint_as_float((unsigned)h << 16);
    unsigned short l = bf16_rne(f - hf);
    int kk = k >> 5, quad = (k >> 3) & 3, j = k & 7;
    int frag = ((kk * 4 + quad) * 128 + n) * 8 + j;
    wpk[(size_t)mat * 32768 + frag] = (short)h;
    wpk[(size_t)mat * 32768 + 16384 + frag] = (short)l;
}

// scan1 + isq fused
__global__ void scan1_kernel(const int* __restrict__ degi, int* __restrict__ rowptr,
                             int* __restrict__ bsum, float* __restrict__ isq) {
    __shared__ int s[256];
    int t = threadIdx.x;
    int i = blockIdx.x * 256 + t;
    int v = (i < N_NODES) ? degi[i] : 0;
    if (i < N_NODES) isq[i] = rsqrtf((float)v + 1.0f);
    s[t] = v;
    __syncthreads();
    for (int off = 1; off < 256; off <<= 1) {
        int add = (t >= off) ? s[t - off] : 0;
        __syncthreads();
        s[t] += add;
        __syncthreads();
    }
    if (i < N_NODES) rowptr[i + 1] = s[t];
    if (t == 255) bsum[blockIdx.x] = s[255];
}

// scan2+scan3 merged: every block redundantly scans the 157 block sums in LDS
// (~2 us, parallel across blocks) and applies its own exclusive offset.
__global__ void scan23_kernel(const int* __restrict__ bsum, int* __restrict__ rowptr, int nb) {
    __shared__ int s[256];
    int t = threadIdx.x;
    int v = (t < nb) ? bsum[t] : 0;
    s[t] = v;
    __syncthreads();
    for (int off = 1; off < 256; off <<= 1) {
        int add = (t >= off) ? s[t - off] : 0;
        __syncthreads();
        s[t] += add;
        __syncthreads();
    }
    int bid = blockIdx.x;
    int boff = (bid > 0) ? s[bid - 1] : 0;   // exclusive prefix of this block
    int i = bid * 256 + t;
    if (i < N_NODES) rowptr[i + 1] += boff;
    if (i == 0 && bid == 0) rowptr[0] = 0;
}

// ---------------------------------------------------------------- GEMM core
// R8 structure: 32 rows / 1 wave / 64-thread blocks (1250 blocks). Identical
// per-wave geometry and numerics to R6's proven 2-wave kernel (32 rows/wave,
// zero barriers, wave-private tbuf) — only the block-quantization changes:
// 625 blocks @ 2.44/CU had a 3-round critical path (113 CUs ran 3 blocks);
// 1250 blocks @ 4.88/CU runs a 5-vs-4 tail ≈ 2.5 rounds of 64-row work.
// (R7 lesson: 4-wave col-split with barriers + LDS LN round-trip REGRESSED
// 40->53 us, bank conflicts 2x — barrier-free beats wave count here.)

// Split an 8-float A sliver into bf16 hi/lo fragments.
__device__ __forceinline__ void split8(const float* av, short8& ahi, short8& alo) {
#pragma unroll
    for (int j = 0; j < 8; ++j) {
        unsigned short hb = bf16_rne(av[j]);
        ahi[j] = (short)hb;
        alo[j] = (short)bf16_rne(av[j] - __uint_as_float((unsigned)hb << 16));
    }
}

// Load 8 hi + 8 lo B-fragments straight from L2-resident packed W, feed TWO
// 16-row A-tiles (32 rows/wave): each B-load pair serves 6 MFMAs (R1 lesson:
// 16 rows/wave doubled B-side L2 traffic and refunded the barrier-removal win).
__device__ __forceinline__ void bload_mfma2(const short* __restrict__ bh,
                                            short8 ahi0, short8 alo0,
                                            short8 ahi1, short8 alo1,
                                            floatx4* acc0, floatx4* acc1) {
    short8 bhi[8], blo[8];
#pragma unroll
    for (int c = 0; c < 8; ++c) {
        bhi[c] = *(const short8*)(bh + c * 128);
        blo[c] = *(const short8*)(bh + 16384 + c * 128);
    }
#pragma unroll
    for (int c = 0; c < 8; ++c) {
        acc0[c] = __builtin_amdgcn_mfma_f32_16x16x32_bf16(ahi0, bhi[c], acc0[c], 0, 0, 0);
        acc0[c] = __builtin_amdgcn_mfma_f32_16x16x32_bf16(alo0, bhi[c], acc0[c], 0, 0, 0);
        acc0[c] = __builtin_amdgcn_mfma_f32_16x16x32_bf16(ahi0, blo[c], acc0[c], 0, 0, 0);
        acc1[c] = __builtin_amdgcn_mfma_f32_16x16x32_bf16(ahi1, bhi[c], acc1[c], 0, 0, 0);
        acc1[c] = __builtin_amdgcn_mfma_f32_16x16x32_bf16(alo1, bhi[c], acc1[c], 0, 0, 0);
        acc1[c] = __builtin_amdgcn_mfma_f32_16x16x32_bf16(ahi1, blo[c], acc1[c], 0, 0, 0);
    }
}

// VARIANT 0 (pre+conv0):  T = A@W1+b1 -> tbuf and fp32 OutG(H); OutC = fp16(T@W2)
// VARIANT 1 (FFN+conv):   T = relu(A@W1+b1) -> tbuf;
//                         Hn = LN(T@W2+b2+Res) -> tbuf and fp32 OutG(H);
//                         OutC = fp16(Hn@W3)
template <int VARIANT>
__device__ __forceinline__ void gemm_core(int tid, int bid,
                                          const float* __restrict__ A, const short* __restrict__ W1pk,
                                          const float* __restrict__ b1, const short* __restrict__ W2pk,
                                          const float* __restrict__ b2, const float* __restrict__ Res,
                                          const float* __restrict__ gamma, const float* __restrict__ beta,
                                          const short* __restrict__ W3pk,
                                          float* __restrict__ OutG, __half* __restrict__ OutC) {
    __shared__ float tbuf[32 * TSTRIDE];    // 16.9 KB wave-private rows (only LDS)
    const int lane = tid & 63;
    const int row0 = bid * 32;
    const int m = lane & 15;
    const int quad = lane >> 4;

    floatx4 acc[2][8];
#pragma unroll
    for (int t = 0; t < 2; ++t)
#pragma unroll
        for (int c = 0; c < 8; ++c) acc[t][c] = (floatx4){0.f, 0.f, 0.f, 0.f};

    const float* arow0 = A + (size_t)(row0 + m) * CH + quad * 8;
    const float* arow1 = arow0 + (size_t)16 * CH;
    float* trow_w = tbuf;                                    // epilogue writes
    const float* trow0 = tbuf + m * TSTRIDE + quad * 8;      // A-frag reads
    const float* trow1 = trow0 + 16 * TSTRIDE;
    // per-lane B-fragment position inside a packed W plane:
    // hi addr = Wpk + kk*4096 + quad*1024 + m*8 + c*128 ; lo at +16384
    const int boff = quad * 1024 + m * 8;

    // ---------------- GEMM 1: A @ W1 ----------------
#pragma unroll 1
    for (int kk = 0; kk < 4; ++kk) {
        float4 a0 = *(const float4*)(arow0 + kk * 32);
        float4 a1 = *(const float4*)(arow0 + kk * 32 + 4);
        float4 a2 = *(const float4*)(arow1 + kk * 32);
        float4 a3 = *(const float4*)(arow1 + kk * 32 + 4);
        float av0[8] = {a0.x, a0.y, a0.z, a0.w, a1.x, a1.y, a1.z, a1.w};
        float av1[8] = {a2.x, a2.y, a2.z, a2.w, a3.x, a3.y, a3.z, a3.w};
        short8 ahi0, alo0, ahi1, alo1;
        split8(av0, ahi0, alo0);
        split8(av1, ahi1, alo1);
        bload_mfma2(W1pk + kk * 4096 + boff, ahi0, alo0, ahi1, alo1, acc[0], acc[1]);
    }

    // T epilogue -> tbuf (and H to global for VARIANT 0); wave-private
#pragma unroll
    for (int t = 0; t < 2; ++t)
#pragma unroll
    for (int c = 0; c < 8; ++c) {
        int col = c * 16 + m;
        float bv = b1[col];
#pragma unroll
        for (int r = 0; r < 4; ++r) {
            int lrow = t * 16 + quad * 4 + r;
            float v = acc[t][c][r] + bv;
            if (VARIANT == 1) v = fmaxf(v, 0.f);
            trow_w[lrow * TSTRIDE + col] = v;
            if (VARIANT == 0)
                OutG[(size_t)(row0 + lrow) * CH + col] = v;
        }
        acc[t][c] = (floatx4){0.f, 0.f, 0.f, 0.f};
    }

    // ---------------- GEMM 2: T @ W2 ----------------
#pragma unroll 1
    for (int kk = 0; kk < 4; ++kk) {
        float av0[8], av1[8];
#pragma unroll
        for (int j = 0; j < 8; ++j) av0[j] = trow0[kk * 32 + j];
#pragma unroll
        for (int j = 0; j < 8; ++j) av1[j] = trow1[kk * 32 + j];
        short8 ahi0, alo0, ahi1, alo1;
        split8(av0, ahi0, alo0);
        split8(av1, ahi1, alo1);
        bload_mfma2(W2pk + kk * 4096 + boff, ahi0, alo0, ahi1, alo1, acc[0], acc[1]);
    }

    if (VARIANT == 0) {
        // conv0 out: plain acc -> fp16 (conv bias applied in agg)
#pragma unroll
        for (int t = 0; t < 2; ++t)
#pragma unroll
        for (int c = 0; c < 8; ++c) {
            int col = c * 16 + m;
#pragma unroll
            for (int r = 0; r < 4; ++r) {
                int row = row0 + t * 16 + quad * 4 + r;
                OutC[(size_t)row * CH + col] = __float2half(acc[t][c][r]);
            }
        }
        return;
    }

    // ---------------- FFN epilogue: LN(acc + b2 + Res) ----------------
#pragma unroll
    for (int t = 0; t < 2; ++t)
#pragma unroll
    for (int c = 0; c < 8; ++c) {
        int col = c * 16 + m;
        float bv = b2[col];
#pragma unroll
        for (int r = 0; r < 4; ++r)
            acc[t][c][r] += bv + Res[(size_t)(row0 + t * 16 + quad * 4 + r) * CH + col];
    }
#pragma unroll
    for (int t = 0; t < 2; ++t)
#pragma unroll
    for (int r = 0; r < 4; ++r) {
        float s = 0.f, q = 0.f;
#pragma unroll
        for (int c = 0; c < 8; ++c) {
            float v = acc[t][c][r];
            s += v;
            q = fmaf(v, v, q);
        }
#pragma unroll
        for (int msk = 1; msk < 16; msk <<= 1) {
            s += __shfl_xor(s, msk);
            q += __shfl_xor(q, msk);
        }
        float mean = s * (1.f / CH);
        float var = q * (1.f / CH) - mean * mean;
        float rstd = rsqrtf(var + LN_EPS);
        int lrow = t * 16 + quad * 4 + r;
        int row = row0 + lrow;
#pragma unroll
        for (int c = 0; c < 8; ++c) {
            int col = c * 16 + m;
            float y = (acc[t][c][r] - mean) * rstd * gamma[col] + beta[col];
            OutG[(size_t)row * CH + col] = y;
            trow_w[lrow * TSTRIDE + col] = y;   // wave-private: no barrier needed
        }
    }
#pragma unroll
    for (int t = 0; t < 2; ++t)
#pragma unroll
    for (int c = 0; c < 8; ++c) acc[t][c] = (floatx4){0.f, 0.f, 0.f, 0.f};

    // ---------------- GEMM 3: Hn @ W3 (next layer's conv) ----------------
#pragma unroll 1
    for (int kk = 0; kk < 4; ++kk) {
        float av0[8], av1[8];
#pragma unroll
        for (int j = 0; j < 8; ++j) av0[j] = trow0[kk * 32 + j];
#pragma unroll
        for (int j = 0; j < 8; ++j) av1[j] = trow1[kk * 32 + j];
        short8 ahi0, alo0, ahi1, alo1;
        split8(av0, ahi0, alo0);
        split8(av1, ahi1, alo1);
        bload_mfma2(W3pk + kk * 4096 + boff, ahi0, alo0, ahi1, alo1, acc[0], acc[1]);
    }

#pragma unroll
    for (int t = 0; t < 2; ++t)
#pragma unroll
    for (int c = 0; c < 8; ++c) {
        int col = c * 16 + m;
#pragma unroll
        for (int r = 0; r < 4; ++r) {
            int row = row0 + t * 16 + quad * 4 + r;
            OutC[(size_t)row * CH + col] = __float2half(acc[t][c][r]);
        }
    }
}

// variant-1 standalone kernel (FFN+conv triple-fusion), 1-wave blocks
template <int VARIANT>
__launch_bounds__(64, 2)
__global__ void gemm_fused(const float* __restrict__ A, const short* __restrict__ W1pk,
                           const float* __restrict__ b1, const short* __restrict__ W2pk,
                           const float* __restrict__ b2, const float* __restrict__ Res,
                           const float* __restrict__ gamma, const float* __restrict__ beta,
                           const short* __restrict__ W3pk,
                           float* __restrict__ OutG, __half* __restrict__ OutC) {
    gemm_core<VARIANT>(threadIdx.x, blockIdx.x, A, W1pk, b1, W2pk, b2, Res,
                       gamma, beta, W3pk, OutG, OutC);
}

// Co-launch: blocks [0,GBLK2) = variant-0 gemm (pre-scaler + conv0, 1 wave);
// blocks [GBLK2,GBLK2+FBLK64) = fill_csr hiding under the gemm latency shadow
// (R6: fill added only ~5 us to the gemm0 dispatch).
__launch_bounds__(64, 2)
__global__ void fillgemm0_kernel(const int* __restrict__ ei, const int* __restrict__ rowptr,
                                 int* __restrict__ fill, int* __restrict__ srcs,
                                 const float* __restrict__ A, const short* __restrict__ W1pk,
                                 const float* __restrict__ b1, const short* __restrict__ W2pk,
                                 float* __restrict__ OutG, __half* __restrict__ OutC) {
    int bid = blockIdx.x;
    if (bid < GBLK2) {
        gemm_core<0>(threadIdx.x, bid, A, W1pk, b1, W2pk, nullptr, nullptr,
                     nullptr, nullptr, nullptr, OutG, OutC);
        return;
    }
    int e = (bid - GBLK2) * 64 + threadIdx.x;
    int s = ei[e];
    int d = ei[N_EDGES + e];
    int pos = atomicAdd(&fill[d], 1);
    srcs[rowptr[d] + pos] = s;
}

// ---------------------------------------------------------------- aggregation
// One wave per dst node, HW fp16, out fp32. 8-deep manual load prefetch;
// fmas retired strictly in j-order (R5/R8/R9: reorder -> 7.3e-4 fail).
// FUSED=1: Hres = relu(LN(agg+bias)) + Hres.  FUSED=0: Out = agg+bias.
// (R15 lesson: do NOT fuse pooling via direct atomics.)
template <int FUSED>
__launch_bounds__(256)
__global__ void agg_kernel(const __half* __restrict__ HW, const int* __restrict__ rowptr,
                           const int* __restrict__ srcs, const float* __restrict__ isq,
                           const float* __restrict__ bias, const float* __restrict__ gamma,
                           const float* __restrict__ beta, float* __restrict__ Hres,
                           float* __restrict__ Out) {
    const int lane = threadIdx.x & 63;
    const int node = blockIdx.x * 4 + (threadIdx.x >> 6);
    const int start = rowptr[node];
    const int end = rowptr[node + 1];

    float ax = 0.f, ay = 0.f;
    for (int base = start; base < end; base += 64) {
        int idx = base + lane;
        int clamped = (idx < end) ? idx : (end - 1);
        int sl = srcs[clamped];
        float wl = isq[sl];
        int cnt = end - base;
        if (cnt > 64) cnt = 64;
        int j = 0;
        for (; j + 8 <= cnt; j += 8) {
            int s[8];
            float w[8];
            float2 v[8];
#pragma unroll
            for (int q = 0; q < 8; ++q) {
                s[q] = __shfl(sl, j + q);
                w[q] = __shfl(wl, j + q);
            }
#pragma unroll
            for (int q = 0; q < 8; ++q)
                v[q] = __half22float2(*(const __half2*)(HW + (size_t)s[q] * CH + lane * 2));
#pragma unroll
            for (int q = 0; q < 8; ++q) {
                ax = fmaf(w[q], v[q].x, ax);
                ay = fmaf(w[q], v[q].y, ay);
            }
        }
        for (; j + 4 <= cnt; j += 4) {
            int s0 = __shfl(sl, j), s1 = __shfl(sl, j + 1);
            int s2 = __shfl(sl, j + 2), s3 = __shfl(sl, j + 3);
            float w0 = __shfl(wl, j), w1 = __shfl(wl, j + 1);
            float w2 = __shfl(wl, j + 2), w3 = __shfl(wl, j + 3);
            float2 v0 = __half22float2(*(const __half2*)(HW + (size_t)s0 * CH + lane * 2));
            float2 v1 = __half22float2(*(const __half2*)(HW + (size_t)s1 * CH + lane * 2));
            float2 v2 = __half22float2(*(const __half2*)(HW + (size_t)s2 * CH + lane * 2));
            float2 v3 = __half22float2(*(const __half2*)(HW + (size_t)s3 * CH + lane * 2));
            ax = fmaf(w0, v0.x, ax); ay = fmaf(w0, v0.y, ay);
            ax = fmaf(w1, v1.x, ax); ay = fmaf(w1, v1.y, ay);
            ax = fmaf(w2, v2.x, ax); ay = fmaf(w2, v2.y, ay);
            ax = fmaf(w3, v3.x, ax); ay = fmaf(w3, v3.y, ay);
        }
        for (; j < cnt; ++j) {
            int s = __shfl(sl, j);
            float w = __shfl(wl, j);
            float2 vf = __half22float2(*(const __half2*)(HW + (size_t)s * CH + lane * 2));
            ax = fmaf(w, vf.x, ax);
            ay = fmaf(w, vf.y, ay);
        }
    }
    float d = isq[node];
    const __half2 hv = *(const __half2*)(HW + (size_t)node * CH + lane * 2);
    float2 hf = __half22float2(hv);
    const float2 bb = *(const float2*)(bias + lane * 2);
    float hx = d * ax + d * d * hf.x + bb.x;
    float hy = d * ay + d * d * hf.y + bb.y;

    if (!FUSED) {
        float2 o; o.x = hx; o.y = hy;
        *(float2*)(Out + (size_t)node * CH + lane * 2) = o;
        return;
    }
    float sum = hx + hy;
    float sq = hx * hx + hy * hy;
    for (int msk = 1; msk < 64; msk <<= 1) {
        sum += __shfl_xor(sum, msk);
        sq += __shfl_xor(sq, msk);
    }
    float mean = sum * (1.f / CH);
    float var = sq * (1.f / CH) - mean * mean;
    float rstd = rsqrtf(var + LN_EPS);
    const float2 gg = *(const float2*)(gamma + lane * 2);
    const float2 be = *(const float2*)(beta + lane * 2);
    float y0 = (hx - mean) * rstd * gg.x + be.x;
    float y1 = (hy - mean) * rstd * gg.y + be.y;
    float2* hp = (float2*)(Hres + (size_t)node * CH + lane * 2);
    float2 rr = *hp;
    float2 o;
    o.x = fmaxf(y0, 0.f) + rr.x;
    o.y = fmaxf(y1, 0.f) + rr.y;
    *hp = o;
}

// ---------------------------------------------------------------- pooling
__launch_bounds__(256)
__global__ void pool_kernel(const float* __restrict__ H, const int* __restrict__ batch,
                            float* __restrict__ g, float* __restrict__ cntf) {
    const int lane = threadIdx.x & 63;
    const int w = blockIdx.x * 4 + (threadIdx.x >> 6);
    const int n0 = w * 16;
    float lx = 0.f, ly = 0.f;
    int run = 0;
    int cur = batch[n0];
    for (int t = 0; t < 16; ++t) {
        int n = n0 + t;
        int b = batch[n];
        if (b != cur) {
            atomicAdd(&g[(size_t)cur * CH + lane * 2], lx);
            atomicAdd(&g[(size_t)cur * CH + lane * 2 + 1], ly);
            if (lane == 0) atomicAdd(&cntf[cur], (float)run);
            lx = ly = 0.f; run = 0; cur = b;
        }
        const float2 v = *(const float2*)(H + (size_t)n * CH + lane * 2);
        lx += v.x; ly += v.y; ++run;
    }
    atomicAdd(&g[(size_t)cur * CH + lane * 2], lx);
    atomicAdd(&g[(size_t)cur * CH + lane * 2 + 1], ly);
    if (lane == 0) atomicAdd(&cntf[cur], (float)run);
}

// ---------------------------------------------------------------- classifier
__launch_bounds__(128)
__global__ void cls_kernel(const float* __restrict__ g, const float* __restrict__ cntf,
                           const float* __restrict__ w1, const float* __restrict__ b1,
                           const float* __restrict__ w2, const float* __restrict__ b2,
                           float* __restrict__ out) {
    __shared__ float gm[CH];
    __shared__ float red[2];
    const int b = blockIdx.x;
    const int t = threadIdx.x;
    float inv = 1.f / fmaxf(cntf[b], 1.f);
    gm[t] = g[(size_t)b * CH + t] * inv;
    __syncthreads();
    float acc = b1[t];
    for (int k = 0; k < CH; ++k) acc = fmaf(gm[k], w1[(size_t)k * CH + t], acc);
    float v = fmaxf(acc, 0.f) * w2[t];
    for (int msk = 1; msk < 64; msk <<= 1) v += __shfl_xor(v, msk);
    if ((t & 63) == 0) red[t >> 6] = v;
    __syncthreads();
    if (t == 0) out[b] = red[0] + red[1] + b2[0];
}

// ---------------------------------------------------------------- launch

extern "C" void kernel_launch(void* const* d_in, const int* in_sizes, int n_in,
                              void* d_out, int out_size, void* d_ws, size_t ws_size,
                              hipStream_t stream) {
    const float* x      = (const float*)d_in[0];
    const int*   ei     = (const int*)d_in[1];
    const int*   batch  = (const int*)d_in[2];
    const float* pre_w  = (const float*)d_in[3];
    const float* pre_b  = (const float*)d_in[4];
    const float* conv_w = (const float*)d_in[5];
    const float* conv_b = (const float*)d_in[6];
    const float* ln_g   = (const float*)d_in[7];
    const float* ln_b   = (const float*)d_in[8];
    const float* ffn_w1 = (const float*)d_in[9];
    const float* ffn_b1 = (const float*)d_in[10];
    const float* ffn_w2 = (const float*)d_in[11];
    const float* ffn_b2 = (const float*)d_in[12];
    const float* fln_g  = (const float*)d_in[13];
    const float* fln_b  = (const float*)d_in[14];
    const float* cls_w1 = (const float*)d_in[15];
    const float* cls_b1 = (const float*)d_in[16];
    const float* cls_w2 = (const float*)d_in[17];
    const float* cls_b2 = (const float*)d_in[18];

    float* H    = (float*)d_ws;                       // 40000*128 f32 (residual)
    float* T    = H + (size_t)N_NODES * CH;           // f32 (final agg out)
    float* R    = T + (size_t)N_NODES * CH;           // scratch
    __half* HWh = (__half*)R;                         // conv out fp16 (alias)
    int*   degi = (int*)(R + (size_t)N_NODES * CH);
    int*   fill = degi + N_NODES;
    float* g    = (float*)(fill + N_NODES);           // zero zone contiguous
    float* cntf = g + (size_t)NB * CH;
    float* isq  = cntf + NB;
    int*  rowptr = (int*)(isq + N_NODES);
    int*  bsum   = rowptr + N_NODES + 1;
    int*  boff   = bsum + 256;
    int*  srcs   = boff + 256;
    short* wpk   = (short*)(srcs + N_EDGES);          // 8 x 32768 shorts

    const int nb_scan = (N_NODES + 255) / 256;  // 157

    hipMemsetAsync(degi, 0, (size_t)(2 * N_NODES + NB * CH + NB) * sizeof(int), stream);

    // deg (atomics) + W pack co-launched (independent)
    degpack_kernel<<<FBLK + 512, 256, 0, stream>>>(ei, degi, pre_w, conv_w,
                                                   ffn_w1, ffn_w2, wpk);
    scan1_kernel<<<nb_scan, 256, 0, stream>>>(degi, rowptr, bsum, isq);
    scan23_kernel<<<nb_scan, 256, 0, stream>>>(bsum, rowptr, nb_scan);
    // fill_csr + (pre-scaler + conv0 gemm) co-launched (independent)
    fillgemm0_kernel<<<GBLK2 + FBLK64, 64, 0, stream>>>(ei, rowptr, fill, srcs,
                                                        x, wpk, pre_b,
                                                        wpk + 1 * 32768, H, HWh);

    const int lblk = N_NODES / 4;    // 10000

    for (int i = 0; i < NL; ++i) {
        if (i < NL - 1) {
            // H = relu(LN(agg(HWh)+conv_b)) + H   (fused)
            agg_kernel<1><<<lblk, 256, 0, stream>>>(HWh, rowptr, srcs, isq,
                                                    conv_b + (size_t)i * CH,
                                                    ln_g + (size_t)i * CH,
                                                    ln_b + (size_t)i * CH, H, nullptr);
            // H = LN(relu(H@w1+b1)@w2+b2+H); HWh = fp16(H@conv_w[i+1])  (triple-fused)
            gemm_fused<1><<<GBLK2, 64, 0, stream>>>(H, wpk + (size_t)(4 + i) * 32768,
                                                    ffn_b1 + (size_t)i * CH,
                                                    wpk + (size_t)(6 + i) * 32768,
                                                    ffn_b2 + (size_t)i * CH, H,
                                                    fln_g + (size_t)i * CH,
                                                    fln_b + (size_t)i * CH,
                                                    wpk + (size_t)(2 + i) * 32768,
                                                    H, HWh);
        } else {
            // T = agg(HWh) + conv_b   (fp32)
            agg_kernel<0><<<lblk, 256, 0, stream>>>(HWh, rowptr, srcs, isq,
                                                    conv_b + (size_t)i * CH,
                                                    nullptr, nullptr, nullptr, T);
        }
    }

    pool_kernel<<<N_NODES / 64, 256, 0, stream>>>(T, batch, g, cntf);
    cls_kernel<<<NB, CH, 0, stream>>>(g, cntf, cls_w1, cls_b1, cls_w2, cls_b2,
                                      (float*)d_out);
}

// Round 11
// 339.294 us; speedup vs baseline: 1.0458x; 1.0080x over previous
//
#include <hip/hip_runtime.h>
#include <hip/hip_fp16.h>
#include <cstdint>
#include <cstddef>

#define N_NODES 40000
#define N_EDGES 640000
#define CH 128
#define NL 3
#define NB 64
#define LN_EPS 1e-5f
#define TSTRIDE 132  // tbuf row stride (floats): 16B-aligned, conflict-free
#define GBLK 625     // gemm blocks (N_NODES/64)
#define FBLK 2500    // fill blocks (N_EDGES/256)

typedef short short8 __attribute__((ext_vector_type(8)));
typedef float floatx4 __attribute__((ext_vector_type(4)));

__device__ __forceinline__ unsigned short bf16_rne(float f) {
    unsigned int u = __float_as_uint(f);
    unsigned int r = u + 0x7FFF + ((u >> 16) & 1);
    return (unsigned short)(r >> 16);
}

// Cross-lane LDS write->read boundary fence (insurance: the tbuf handoff is
// cross-lane, so compiler alias analysis sees no dep between lane X's
// ds_writes and lane Y's ds_reads). R9/R10's absmax failure was NOT this —
// it was a 256-thread launch into a 128-launch_bounds kernel (launch
// silently failed; gemm_fused<1> never ran). Fence kept: 2 insts/boundary.
__device__ __forceinline__ void lds_fence() {
    asm volatile("s_waitcnt lgkmcnt(0)" ::: "memory");
    __builtin_amdgcn_sched_barrier(0);
}

// ---------------------------------------------------------------- CSR build + W pack
// deg (2500 blocks) and pack (512 blocks) are independent -> one launch.
// W pack layout per matrix: [hi 16384 | lo 16384] bf16 shorts (64 KB).
// B-fragment layout for mfma_f32_16x16x32_bf16:
// frag[((kk*4+quad)*128 + n)*8 + j], k=kk*32+quad*8+j.
// bf16 split keeps lo NORMAL; fp16 split FAILED (R5/R6: lo subnormal, flushed).
__launch_bounds__(256)
__global__ void degpack_kernel(const int* __restrict__ ei, int* __restrict__ degi,
                               const float* __restrict__ pre_w, const float* __restrict__ conv_w,
                               const float* __restrict__ ffn_w1, const float* __restrict__ ffn_w2,
                               short* __restrict__ wpk) {
    int bid = blockIdx.x;
    if (bid < FBLK) {
        int e = bid * 256 + threadIdx.x;
        atomicAdd(&degi[ei[N_EDGES + e]], 1);
        return;
    }
    int idx = (bid - FBLK) * 256 + threadIdx.x;  // 8 * 16384 total
    int mat = idx >> 14;
    int e = idx & 16383;
    int k = e >> 7, n = e & 127;
    const float* src;
    switch (mat) {
        case 0: src = pre_w; break;
        case 1: case 2: case 3: src = conv_w + (size_t)(mat - 1) * 16384; break;
        case 4: case 5: src = ffn_w1 + (size_t)(mat - 4) * 16384; break;
        default: src = ffn_w2 + (size_t)(mat - 6) * 16384; break;
    }
    float f = src[e];
    unsigned short h = bf16_rne(f);
    float hf = __uint_as_float((unsigned)h << 16);
    unsigned short l = bf16_rne(f - hf);
    int kk = k >> 5, quad = (k >> 3) & 3, j = k & 7;
    int frag = ((kk * 4 + quad) * 128 + n) * 8 + j;
    wpk[(size_t)mat * 32768 + frag] = (short)h;
    wpk[(size_t)mat * 32768 + 16384 + frag] = (short)l;
}

// scan1 + isq fused
__global__ void scan1_kernel(const int* __restrict__ degi, int* __restrict__ rowptr,
                             int* __restrict__ bsum, float* __restrict__ isq) {
    __shared__ int s[256];
    int t = threadIdx.x;
    int i = blockIdx.x * 256 + t;
    int v = (i < N_NODES) ? degi[i] : 0;
    if (i < N_NODES) isq[i] = rsqrtf((float)v + 1.0f);
    s[t] = v;
    __syncthreads();
    for (int off = 1; off < 256; off <<= 1) {
        int add = (t >= off) ? s[t - off] : 0;
        __syncthreads();
        s[t] += add;
        __syncthreads();
    }
    if (i < N_NODES) rowptr[i + 1] = s[t];
    if (t == 255) bsum[blockIdx.x] = s[255];
}

// scan2+scan3 merged: every block redundantly scans the 157 block sums in LDS
// (~2 us, parallel across blocks) and applies its own exclusive offset.
__global__ void scan23_kernel(const int* __restrict__ bsum, int* __restrict__ rowptr, int nb) {
    __shared__ int s[256];
    int t = threadIdx.x;
    int v = (t < nb) ? bsum[t] : 0;
    s[t] = v;
    __syncthreads();
    for (int off = 1; off < 256; off <<= 1) {
        int add = (t >= off) ? s[t - off] : 0;
        __syncthreads();
        s[t] += add;
        __syncthreads();
    }
    int bid = blockIdx.x;
    int boff = (bid > 0) ? s[bid - 1] : 0;   // exclusive prefix of this block
    int i = bid * 256 + t;
    if (i < N_NODES) rowptr[i + 1] += boff;
    if (i == 0 && bid == 0) rowptr[0] = 0;
}

// ---------------------------------------------------------------- GEMM core (R6 structure)
// 2 waves/block, 32 rows/wave (64-row block, 625 blocks exact). Wave-private
// tbuf rows -> ZERO barriers. B direct from L2-hot packed W.
// R11: kk loops fully unrolled (scheduler hoists next iteration's B-loads
// above current MFMA block, counted vmcnt) + lds_fence at tbuf boundaries.
// CRITICAL: gemm_fused<1> must be launched with 128 threads —
// __launch_bounds__(128,2); a 256-thread launch FAILS SILENTLY (R9/R10).

// Split an 8-float A sliver into bf16 hi/lo fragments.
__device__ __forceinline__ void split8(const float* av, short8& ahi, short8& alo) {
#pragma unroll
    for (int j = 0; j < 8; ++j) {
        unsigned short hb = bf16_rne(av[j]);
        ahi[j] = (short)hb;
        alo[j] = (short)bf16_rne(av[j] - __uint_as_float((unsigned)hb << 16));
    }
}

// Load 8 hi + 8 lo B-fragments straight from L2-resident packed W, feed TWO
// 16-row A-tiles (32 rows/wave): each B-load pair serves 6 MFMAs (R1 lesson:
// 16 rows/wave doubled B-side L2 traffic and refunded the barrier-removal win).
__device__ __forceinline__ void bload_mfma2(const short* __restrict__ bh,
                                            short8 ahi0, short8 alo0,
                                            short8 ahi1, short8 alo1,
                                            floatx4* acc0, floatx4* acc1) {
    short8 bhi[8], blo[8];
#pragma unroll
    for (int c = 0; c < 8; ++c) {
        bhi[c] = *(const short8*)(bh + c * 128);
        blo[c] = *(const short8*)(bh + 16384 + c * 128);
    }
#pragma unroll
    for (int c = 0; c < 8; ++c) {
        acc0[c] = __builtin_amdgcn_mfma_f32_16x16x32_bf16(ahi0, bhi[c], acc0[c], 0, 0, 0);
        acc0[c] = __builtin_amdgcn_mfma_f32_16x16x32_bf16(alo0, bhi[c], acc0[c], 0, 0, 0);
        acc0[c] = __builtin_amdgcn_mfma_f32_16x16x32_bf16(ahi0, blo[c], acc0[c], 0, 0, 0);
        acc1[c] = __builtin_amdgcn_mfma_f32_16x16x32_bf16(ahi1, bhi[c], acc1[c], 0, 0, 0);
        acc1[c] = __builtin_amdgcn_mfma_f32_16x16x32_bf16(alo1, bhi[c], acc1[c], 0, 0, 0);
        acc1[c] = __builtin_amdgcn_mfma_f32_16x16x32_bf16(ahi1, blo[c], acc1[c], 0, 0, 0);
    }
}

// VARIANT 0 (pre+conv0):  T = A@W1+b1 -> tbuf and fp32 OutG(H); OutC = fp16(T@W2)
// VARIANT 1 (FFN+conv):   T = relu(A@W1+b1) -> tbuf;
//                         Hn = LN(T@W2+b2+Res) -> tbuf and fp32 OutG(H);
//                         OutC = fp16(Hn@W3)
template <int VARIANT>
__device__ __forceinline__ void gemm_core(int tid, int bid,
                                          const float* __restrict__ A, const short* __restrict__ W1pk,
                                          const float* __restrict__ b1, const short* __restrict__ W2pk,
                                          const float* __restrict__ b2, const float* __restrict__ Res,
                                          const float* __restrict__ gamma, const float* __restrict__ beta,
                                          const short* __restrict__ W3pk,
                                          float* __restrict__ OutG, __half* __restrict__ OutC) {
    __shared__ float tbuf[64 * TSTRIDE];    // 33 KB wave-private rows (only LDS)
    const int lane = tid & 63;
    const int wv = tid >> 6;                 // 0..1
    const int row0 = bid * 64 + wv * 32;
    const int m = lane & 15;
    const int quad = lane >> 4;

    floatx4 acc[2][8];
#pragma unroll
    for (int t = 0; t < 2; ++t)
#pragma unroll
        for (int c = 0; c < 8; ++c) acc[t][c] = (floatx4){0.f, 0.f, 0.f, 0.f};

    const float* arow0 = A + (size_t)(row0 + m) * CH + quad * 8;
    const float* arow1 = arow0 + (size_t)16 * CH;
    float* trow_w = tbuf + (wv * 32) * TSTRIDE;             // epilogue writes
    const float* trow0 = tbuf + (wv * 32 + m) * TSTRIDE + quad * 8;  // A-frag reads
    const float* trow1 = trow0 + 16 * TSTRIDE;
    // per-lane B-fragment position inside a packed W plane:
    // hi addr = Wpk + kk*4096 + quad*1024 + m*8 + c*128 ; lo at +16384
    const int boff = quad * 1024 + m * 8;

    // ---------------- GEMM 1: A @ W1 ----------------
#pragma unroll
    for (int kk = 0; kk < 4; ++kk) {
        float4 a0 = *(const float4*)(arow0 + kk * 32);
        float4 a1 = *(const float4*)(arow0 + kk * 32 + 4);
        float4 a2 = *(const float4*)(arow1 + kk * 32);
        float4 a3 = *(const float4*)(arow1 + kk * 32 + 4);
        float av0[8] = {a0.x, a0.y, a0.z, a0.w, a1.x, a1.y, a1.z, a1.w};
        float av1[8] = {a2.x, a2.y, a2.z, a2.w, a3.x, a3.y, a3.z, a3.w};
        short8 ahi0, alo0, ahi1, alo1;
        split8(av0, ahi0, alo0);
        split8(av1, ahi1, alo1);
        bload_mfma2(W1pk + kk * 4096 + boff, ahi0, alo0, ahi1, alo1, acc[0], acc[1]);
    }

    // T epilogue -> tbuf (and H to global for VARIANT 0); wave-private
#pragma unroll
    for (int t = 0; t < 2; ++t)
#pragma unroll
    for (int c = 0; c < 8; ++c) {
        int col = c * 16 + m;
        float bv = b1[col];
#pragma unroll
        for (int r = 0; r < 4; ++r) {
            int lrow = t * 16 + quad * 4 + r;
            float v = acc[t][c][r] + bv;
            if (VARIANT == 1) v = fmaxf(v, 0.f);
            trow_w[lrow * TSTRIDE + col] = v;
            if (VARIANT == 0)
                OutG[(size_t)(row0 + lrow) * CH + col] = v;
        }
        acc[t][c] = (floatx4){0.f, 0.f, 0.f, 0.f};
    }
    lds_fence();   // cross-lane tbuf handoff: writes above, reads below

    // ---------------- GEMM 2: T @ W2 ----------------
#pragma unroll
    for (int kk = 0; kk < 4; ++kk) {
        float av0[8], av1[8];
#pragma unroll
        for (int j = 0; j < 8; ++j) av0[j] = trow0[kk * 32 + j];
#pragma unroll
        for (int j = 0; j < 8; ++j) av1[j] = trow1[kk * 32 + j];
        short8 ahi0, alo0, ahi1, alo1;
        split8(av0, ahi0, alo0);
        split8(av1, ahi1, alo1);
        bload_mfma2(W2pk + kk * 4096 + boff, ahi0, alo0, ahi1, alo1, acc[0], acc[1]);
    }

    if (VARIANT == 0) {
        // conv0 out: plain acc -> fp16 (conv bias applied in agg)
#pragma unroll
        for (int t = 0; t < 2; ++t)
#pragma unroll
        for (int c = 0; c < 8; ++c) {
            int col = c * 16 + m;
#pragma unroll
            for (int r = 0; r < 4; ++r) {
                int row = row0 + t * 16 + quad * 4 + r;
                OutC[(size_t)row * CH + col] = __float2half(acc[t][c][r]);
            }
        }
        return;
    }

    // ---------------- FFN epilogue: LN(acc + b2 + Res) ----------------
#pragma unroll
    for (int t = 0; t < 2; ++t)
#pragma unroll
    for (int c = 0; c < 8; ++c) {
        int col = c * 16 + m;
        float bv = b2[col];
#pragma unroll
        for (int r = 0; r < 4; ++r)
            acc[t][c][r] += bv + Res[(size_t)(row0 + t * 16 + quad * 4 + r) * CH + col];
    }
#pragma unroll
    for (int t = 0; t < 2; ++t)
#pragma unroll
    for (int r = 0; r < 4; ++r) {
        float s = 0.f, q = 0.f;
#pragma unroll
        for (int c = 0; c < 8; ++c) {
            float v = acc[t][c][r];
            s += v;
            q = fmaf(v, v, q);
        }
#pragma unroll
        for (int msk = 1; msk < 16; msk <<= 1) {
            s += __shfl_xor(s, msk);
            q += __shfl_xor(q, msk);
        }
        float mean = s * (1.f / CH);
        float var = q * (1.f / CH) - mean * mean;
        float rstd = rsqrtf(var + LN_EPS);
        int lrow = t * 16 + quad * 4 + r;
        int row = row0 + lrow;
#pragma unroll
        for (int c = 0; c < 8; ++c) {
            int col = c * 16 + m;
            float y = (acc[t][c][r] - mean) * rstd * gamma[col] + beta[col];
            OutG[(size_t)row * CH + col] = y;
            trow_w[lrow * TSTRIDE + col] = y;   // wave-private rows
        }
    }
#pragma unroll
    for (int t = 0; t < 2; ++t)
#pragma unroll
    for (int c = 0; c < 8; ++c) acc[t][c] = (floatx4){0.f, 0.f, 0.f, 0.f};
    lds_fence();   // cross-lane tbuf handoff: writes above, reads below

    // ---------------- GEMM 3: Hn @ W3 (next layer's conv) ----------------
#pragma unroll
    for (int kk = 0; kk < 4; ++kk) {
        float av0[8], av1[8];
#pragma unroll
        for (int j = 0; j < 8; ++j) av0[j] = trow0[kk * 32 + j];
#pragma unroll
        for (int j = 0; j < 8; ++j) av1[j] = trow1[kk * 32 + j];
        short8 ahi0, alo0, ahi1, alo1;
        split8(av0, ahi0, alo0);
        split8(av1, ahi1, alo1);
        bload_mfma2(W3pk + kk * 4096 + boff, ahi0, alo0, ahi1, alo1, acc[0], acc[1]);
    }

#pragma unroll
    for (int t = 0; t < 2; ++t)
#pragma unroll
    for (int c = 0; c < 8; ++c) {
        int col = c * 16 + m;
#pragma unroll
        for (int r = 0; r < 4; ++r) {
            int row = row0 + t * 16 + quad * 4 + r;
            OutC[(size_t)row * CH + col] = __float2half(acc[t][c][r]);
        }
    }
}

// variant-1 standalone kernel (FFN+conv triple-fusion) — 128 THREADS ONLY
template <int VARIANT>
__launch_bounds__(128, 2)
__global__ void gemm_fused(const float* __restrict__ A, const short* __restrict__ W1pk,
                           const float* __restrict__ b1, const short* __restrict__ W2pk,
                           const float* __restrict__ b2, const float* __restrict__ Res,
                           const float* __restrict__ gamma, const float* __restrict__ beta,
                           const short* __restrict__ W3pk,
                           float* __restrict__ OutG, __half* __restrict__ OutC) {
    gemm_core<VARIANT>(threadIdx.x, blockIdx.x, A, W1pk, b1, W2pk, b2, Res,
                       gamma, beta, W3pk, OutG, OutC);
}

// Co-launch: blocks [0,GBLK) = variant-0 gemm (pre-scaler + conv0; threads
// 128..255 exit immediately — zero barriers in gemm path); blocks
// [GBLK,GBLK+FBLK) = fill_csr hiding under the gemm latency shadow
// (R6: fill added only ~5 us to the gemm0 dispatch).
__launch_bounds__(256, 2)
__global__ void fillgemm0_kernel(const int* __restrict__ ei, const int* __restrict__ rowptr,
                                 int* __restrict__ fill, int* __restrict__ srcs,
                                 const float* __restrict__ A, const short* __restrict__ W1pk,
                                 const float* __restrict__ b1, const short* __restrict__ W2pk,
                                 float* __restrict__ OutG, __half* __restrict__ OutC) {
    int bid = blockIdx.x;
    if (bid < GBLK) {
        if (threadIdx.x >= 128) return;
        gemm_core<0>(threadIdx.x, bid, A, W1pk, b1, W2pk, nullptr, nullptr,
                     nullptr, nullptr, nullptr, OutG, OutC);
        return;
    }
    int e = (bid - GBLK) * 256 + threadIdx.x;
    int s = ei[e];
    int d = ei[N_EDGES + e];
    int pos = atomicAdd(&fill[d], 1);
    srcs[rowptr[d] + pos] = s;
}

// ---------------------------------------------------------------- aggregation
// One wave per dst node, HW fp16, out fp32. 8-deep manual load prefetch;
// fmas retired strictly in j-order (R5/R8/R9: reorder -> 7.3e-4 fail).
// FUSED=1: Hres = relu(LN(agg+bias)) + Hres.  FUSED=0: Out = agg+bias.
// (R15 lesson: do NOT fuse pooling via direct atomics.)
template <int FUSED>
__launch_bounds__(256)
__global__ void agg_kernel(const __half* __restrict__ HW, const int* __restrict__ rowptr,
                           const int* __restrict__ srcs, const float* __restrict__ isq,
                           const float* __restrict__ bias, const float* __restrict__ gamma,
                           const float* __restrict__ beta, float* __restrict__ Hres,
                           float* __restrict__ Out) {
    const int lane = threadIdx.x & 63;
    const int node = blockIdx.x * 4 + (threadIdx.x >> 6);
    const int start = rowptr[node];
    const int end = rowptr[node + 1];

    float ax = 0.f, ay = 0.f;
    for (int base = start; base < end; base += 64) {
        int idx = base + lane;
        int clamped = (idx < end) ? idx : (end - 1);
        int sl = srcs[clamped];
        float wl = isq[sl];
        int cnt = end - base;
        if (cnt > 64) cnt = 64;
        int j = 0;
        for (; j + 8 <= cnt; j += 8) {
            int s[8];
            float w[8];
            float2 v[8];
#pragma unroll
            for (int q = 0; q < 8; ++q) {
                s[q] = __shfl(sl, j + q);
                w[q] = __shfl(wl, j + q);
            }
#pragma unroll
            for (int q = 0; q < 8; ++q)
                v[q] = __half22float2(*(const __half2*)(HW + (size_t)s[q] * CH + lane * 2));
#pragma unroll
            for (int q = 0; q < 8; ++q) {
                ax = fmaf(w[q], v[q].x, ax);
                ay = fmaf(w[q], v[q].y, ay);
            }
        }
        for (; j + 4 <= cnt; j += 4) {
            int s0 = __shfl(sl, j), s1 = __shfl(sl, j + 1);
            int s2 = __shfl(sl, j + 2), s3 = __shfl(sl, j + 3);
            float w0 = __shfl(wl, j), w1 = __shfl(wl, j + 1);
            float w2 = __shfl(wl, j + 2), w3 = __shfl(wl, j + 3);
            float2 v0 = __half22float2(*(const __half2*)(HW + (size_t)s0 * CH + lane * 2));
            float2 v1 = __half22float2(*(const __half2*)(HW + (size_t)s1 * CH + lane * 2));
            float2 v2 = __half22float2(*(const __half2*)(HW + (size_t)s2 * CH + lane * 2));
            float2 v3 = __half22float2(*(const __half2*)(HW + (size_t)s3 * CH + lane * 2));
            ax = fmaf(w0, v0.x, ax); ay = fmaf(w0, v0.y, ay);
            ax = fmaf(w1, v1.x, ax); ay = fmaf(w1, v1.y, ay);
            ax = fmaf(w2, v2.x, ax); ay = fmaf(w2, v2.y, ay);
            ax = fmaf(w3, v3.x, ax); ay = fmaf(w3, v3.y, ay);
        }
        for (; j < cnt; ++j) {
            int s = __shfl(sl, j);
            float w = __shfl(wl, j);
            float2 vf = __half22float2(*(const __half2*)(HW + (size_t)s * CH + lane * 2));
            ax = fmaf(w, vf.x, ax);
            ay = fmaf(w, vf.y, ay);
        }
    }
    float d = isq[node];
    const __half2 hv = *(const __half2*)(HW + (size_t)node * CH + lane * 2);
    float2 hf = __half22float2(hv);
    const float2 bb = *(const float2*)(bias + lane * 2);
    float hx = d * ax + d * d * hf.x + bb.x;
    float hy = d * ay + d * d * hf.y + bb.y;

    if (!FUSED) {
        float2 o; o.x = hx; o.y = hy;
        *(float2*)(Out + (size_t)node * CH + lane * 2) = o;
        return;
    }
    float sum = hx + hy;
    float sq = hx * hx + hy * hy;
    for (int msk = 1; msk < 64; msk <<= 1) {
        sum += __shfl_xor(sum, msk);
        sq += __shfl_xor(sq, msk);
    }
    float mean = sum * (1.f / CH);
    float var = sq * (1.f / CH) - mean * mean;
    float rstd = rsqrtf(var + LN_EPS);
    const float2 gg = *(const float2*)(gamma + lane * 2);
    const float2 be = *(const float2*)(beta + lane * 2);
    float y0 = (hx - mean) * rstd * gg.x + be.x;
    float y1 = (hy - mean) * rstd * gg.y + be.y;
    float2* hp = (float2*)(Hres + (size_t)node * CH + lane * 2);
    float2 rr = *hp;
    float2 o;
    o.x = fmaxf(y0, 0.f) + rr.x;
    o.y = fmaxf(y1, 0.f) + rr.y;
    *hp = o;
}

// ---------------------------------------------------------------- pooling
__launch_bounds__(256)
__global__ void pool_kernel(const float* __restrict__ H, const int* __restrict__ batch,
                            float* __restrict__ g, float* __restrict__ cntf) {
    const int lane = threadIdx.x & 63;
    const int w = blockIdx.x * 4 + (threadIdx.x >> 6);
    const int n0 = w * 16;
    float lx = 0.f, ly = 0.f;
    int run = 0;
    int cur = batch[n0];
    for (int t = 0; t < 16; ++t) {
        int n = n0 + t;
        int b = batch[n];
        if (b != cur) {
            atomicAdd(&g[(size_t)cur * CH + lane * 2], lx);
            atomicAdd(&g[(size_t)cur * CH + lane * 2 + 1], ly);
            if (lane == 0) atomicAdd(&cntf[cur], (float)run);
            lx = ly = 0.f; run = 0; cur = b;
        }
        const float2 v = *(const float2*)(H + (size_t)n * CH + lane * 2);
        lx += v.x; ly += v.y; ++run;
    }
    atomicAdd(&g[(size_t)cur * CH + lane * 2], lx);
    atomicAdd(&g[(size_t)cur * CH + lane * 2 + 1], ly);
    if (lane == 0) atomicAdd(&cntf[cur], (float)run);
}

// ---------------------------------------------------------------- classifier
__launch_bounds__(128)
__global__ void cls_kernel(const float* __restrict__ g, const float* __restrict__ cntf,
                           const float* __restrict__ w1, const float* __restrict__ b1,
                           const float* __restrict__ w2, const float* __restrict__ b2,
                           float* __restrict__ out) {
    __shared__ float gm[CH];
    __shared__ float red[2];
    const int b = blockIdx.x;
    const int t = threadIdx.x;
    float inv = 1.f / fmaxf(cntf[b], 1.f);
    gm[t] = g[(size_t)b * CH + t] * inv;
    __syncthreads();
    float acc = b1[t];
    for (int k = 0; k < CH; ++k) acc = fmaf(gm[k], w1[(size_t)k * CH + t], acc);
    float v = fmaxf(acc, 0.f) * w2[t];
    for (int msk = 1; msk < 64; msk <<= 1) v += __shfl_xor(v, msk);
    if ((t & 63) == 0) red[t >> 6] = v;
    __syncthreads();
    if (t == 0) out[b] = red[0] + red[1] + b2[0];
}

// ---------------------------------------------------------------- launch

extern "C" void kernel_launch(void* const* d_in, const int* in_sizes, int n_in,
                              void* d_out, int out_size, void* d_ws, size_t ws_size,
                              hipStream_t stream) {
    const float* x      = (const float*)d_in[0];
    const int*   ei     = (const int*)d_in[1];
    const int*   batch  = (const int*)d_in[2];
    const float* pre_w  = (const float*)d_in[3];
    const float* pre_b  = (const float*)d_in[4];
    const float* conv_w = (const float*)d_in[5];
    const float* conv_b = (const float*)d_in[6];
    const float* ln_g   = (const float*)d_in[7];
    const float* ln_b   = (const float*)d_in[8];
    const float* ffn_w1 = (const float*)d_in[9];
    const float* ffn_b1 = (const float*)d_in[10];
    const float* ffn_w2 = (const float*)d_in[11];
    const float* ffn_b2 = (const float*)d_in[12];
    const float* fln_g  = (const float*)d_in[13];
    const float* fln_b  = (const float*)d_in[14];
    const float* cls_w1 = (const float*)d_in[15];
    const float* cls_b1 = (const float*)d_in[16];
    const float* cls_w2 = (const float*)d_in[17];
    const float* cls_b2 = (const float*)d_in[18];

    float* H    = (float*)d_ws;                       // 40000*128 f32 (residual)
    float* T    = H + (size_t)N_NODES * CH;           // f32 (final agg out)
    float* R    = T + (size_t)N_NODES * CH;           // scratch
    __half* HWh = (__half*)R;                         // conv out fp16 (alias)
    int*   degi = (int*)(R + (size_t)N_NODES * CH);
    int*   fill = degi + N_NODES;
    float* g    = (float*)(fill + N_NODES);           // zero zone contiguous
    float* cntf = g + (size_t)NB * CH;
    float* isq  = cntf + NB;
    int*  rowptr = (int*)(isq + N_NODES);
    int*  bsum   = rowptr + N_NODES + 1;
    int*  boff   = bsum + 256;
    int*  srcs   = boff + 256;
    short* wpk   = (short*)(srcs + N_EDGES);          // 8 x 32768 shorts

    const int nb_scan = (N_NODES + 255) / 256;  // 157

    hipMemsetAsync(degi, 0, (size_t)(2 * N_NODES + NB * CH + NB) * sizeof(int), stream);

    // deg (atomics) + W pack co-launched (independent)
    degpack_kernel<<<FBLK + 512, 256, 0, stream>>>(ei, degi, pre_w, conv_w,
                                                   ffn_w1, ffn_w2, wpk);
    scan1_kernel<<<nb_scan, 256, 0, stream>>>(degi, rowptr, bsum, isq);
    scan23_kernel<<<nb_scan, 256, 0, stream>>>(bsum, rowptr, nb_scan);
    // fill_csr + (pre-scaler + conv0 gemm) co-launched (independent)
    fillgemm0_kernel<<<GBLK + FBLK, 256, 0, stream>>>(ei, rowptr, fill, srcs,
                                                      x, wpk, pre_b,
                                                      wpk + 1 * 32768, H, HWh);

    const int lblk = N_NODES / 4;    // 10000

    for (int i = 0; i < NL; ++i) {
        if (i < NL - 1) {
            // H = relu(LN(agg(HWh)+conv_b)) + H   (fused)
            agg_kernel<1><<<lblk, 256, 0, stream>>>(HWh, rowptr, srcs, isq,
                                                    conv_b + (size_t)i * CH,
                                                    ln_g + (size_t)i * CH,
                                                    ln_b + (size_t)i * CH, H, nullptr);
            // H = LN(relu(H@w1+b1)@w2+b2+H); HWh = fp16(H@conv_w[i+1])  (triple-fused)
            gemm_fused<1><<<GBLK, 128, 0, stream>>>(H, wpk + (size_t)(4 + i) * 32768,
                                                    ffn_b1 + (size_t)i * CH,
                                                    wpk + (size_t)(6 + i) * 32768,
                                                    ffn_b2 + (size_t)i * CH, H,
                                                    fln_g + (size_t)i * CH,
                                                    fln_b + (size_t)i * CH,
                                                    wpk + (size_t)(2 + i) * 32768,
                                                    H, HWh);
        } else {
            // T = agg(HWh) + conv_b   (fp32)
            agg_kernel<0><<<lblk, 256, 0, stream>>>(HWh, rowptr, srcs, isq,
                                                    conv_b + (size_t)i * CH,
                                                    nullptr, nullptr, nullptr, T);
        }
    }

    pool_kernel<<<N_NODES / 64, 256, 0, stream>>>(T, batch, g, cntf);
    cls_kernel<<<NB, CH, 0, stream>>>(g, cntf, cls_w1, cls_b1, cls_w2, cls_b2,
                                      (float*)d_out);
}

// Round 12
// 330.315 us; speedup vs baseline: 1.0742x; 1.0272x over previous
//
#include <hip/hip_runtime.h>
#include <hip/hip_fp16.h>
#include <cstdint>
#include <cstddef>

#define N_NODES 40000
#define N_EDGES 640000
#define CH 128
#define NL 3
#define NB 64
#define LN_EPS 1e-5f
#define TSTRIDE 132  // tbuf row stride (floats): 16B-aligned, conflict-free
#define GBLK 625     // gemm blocks (N_NODES/64)
#define FBLK 2500    // fill blocks (N_EDGES/256)

typedef short short8 __attribute__((ext_vector_type(8)));
typedef float floatx4 __attribute__((ext_vector_type(4)));

__device__ __forceinline__ unsigned short bf16_rne(float f) {
    unsigned int u = __float_as_uint(f);
    unsigned int r = u + 0x7FFF + ((u >> 16) & 1);
    return (unsigned short)(r >> 16);
}

// Cross-lane LDS write->read boundary fence (insurance; the tbuf handoff is
// cross-lane so compiler alias analysis sees no dep). 2 insts/boundary.
__device__ __forceinline__ void lds_fence() {
    asm volatile("s_waitcnt lgkmcnt(0)" ::: "memory");
    __builtin_amdgcn_sched_barrier(0);
}

// ---------------------------------------------------------------- CSR build + W pack
// deg (2500 blocks) and pack (512 blocks) are independent -> one launch.
// W pack layout per matrix: [hi 16384 | lo 16384] bf16 shorts (64 KB).
// B-fragment layout for mfma_f32_16x16x32_bf16:
// frag[((kk*4+quad)*128 + n)*8 + j], k=kk*32+quad*8+j.
// bf16 split keeps lo NORMAL; fp16 split FAILED (R5/R6: lo subnormal, flushed).
__launch_bounds__(256)
__global__ void degpack_kernel(const int* __restrict__ ei, int* __restrict__ degi,
                               const float* __restrict__ pre_w, const float* __restrict__ conv_w,
                               const float* __restrict__ ffn_w1, const float* __restrict__ ffn_w2,
                               short* __restrict__ wpk) {
    int bid = blockIdx.x;
    if (bid < FBLK) {
        int e = bid * 256 + threadIdx.x;
        atomicAdd(&degi[ei[N_EDGES + e]], 1);
        return;
    }
    int idx = (bid - FBLK) * 256 + threadIdx.x;  // 8 * 16384 total
    int mat = idx >> 14;
    int e = idx & 16383;
    int k = e >> 7, n = e & 127;
    const float* src;
    switch (mat) {
        case 0: src = pre_w; break;
        case 1: case 2: case 3: src = conv_w + (size_t)(mat - 1) * 16384; break;
        case 4: case 5: src = ffn_w1 + (size_t)(mat - 4) * 16384; break;
        default: src = ffn_w2 + (size_t)(mat - 6) * 16384; break;
    }
    float f = src[e];
    unsigned short h = bf16_rne(f);
    float hf = __uint_as_float((unsigned)h << 16);
    unsigned short l = bf16_rne(f - hf);
    int kk = k >> 5, quad = (k >> 3) & 3, j = k & 7;
    int frag = ((kk * 4 + quad) * 128 + n) * 8 + j;
    wpk[(size_t)mat * 32768 + frag] = (short)h;
    wpk[(size_t)mat * 32768 + 16384 + frag] = (short)l;
}

// scan1 + isq fused
__global__ void scan1_kernel(const int* __restrict__ degi, int* __restrict__ rowptr,
                             int* __restrict__ bsum, float* __restrict__ isq) {
    __shared__ int s[256];
    int t = threadIdx.x;
    int i = blockIdx.x * 256 + t;
    int v = (i < N_NODES) ? degi[i] : 0;
    if (i < N_NODES) isq[i] = rsqrtf((float)v + 1.0f);
    s[t] = v;
    __syncthreads();
    for (int off = 1; off < 256; off <<= 1) {
        int add = (t >= off) ? s[t - off] : 0;
        __syncthreads();
        s[t] += add;
        __syncthreads();
    }
    if (i < N_NODES) rowptr[i + 1] = s[t];
    if (t == 255) bsum[blockIdx.x] = s[255];
}

// scan2+scan3 merged: every block redundantly scans the 157 block sums in LDS
// (~2 us, parallel across blocks) and applies its own exclusive offset.
__global__ void scan23_kernel(const int* __restrict__ bsum, int* __restrict__ rowptr, int nb) {
    __shared__ int s[256];
    int t = threadIdx.x;
    int v = (t < nb) ? bsum[t] : 0;
    s[t] = v;
    __syncthreads();
    for (int off = 1; off < 256; off <<= 1) {
        int add = (t >= off) ? s[t - off] : 0;
        __syncthreads();
        s[t] += add;
        __syncthreads();
    }
    int bid = blockIdx.x;
    int boff = (bid > 0) ? s[bid - 1] : 0;   // exclusive prefix of this block
    int i = bid * 256 + t;
    if (i < N_NODES) rowptr[i + 1] += boff;
    if (i == 0 && bid == 0) rowptr[0] = 0;
}

// ---------------------------------------------------------------- GEMM core (R6 structure)
// 2 waves/block, 32 rows/wave (64-row block, 625 blocks exact). Wave-private
// tbuf rows -> ZERO barriers. B direct from L2-hot packed W. kk loops at
// unroll-1 (R6 proven; R11 showed full unroll neutral). lds_fence at tbuf
// boundaries as insurance. CRITICAL: gemm_fused<1> launches with 128 threads
// — a 256-thread launch into __launch_bounds__(128) FAILS SILENTLY (R9/R10).

// Split an 8-float A sliver into bf16 hi/lo fragments.
__device__ __forceinline__ void split8(const float* av, short8& ahi, short8& alo) {
#pragma unroll
    for (int j = 0; j < 8; ++j) {
        unsigned short hb = bf16_rne(av[j]);
        ahi[j] = (short)hb;
        alo[j] = (short)bf16_rne(av[j] - __uint_as_float((unsigned)hb << 16));
    }
}

// Load 8 hi + 8 lo B-fragments straight from L2-resident packed W, feed TWO
// 16-row A-tiles (32 rows/wave): each B-load pair serves 6 MFMAs (R1 lesson:
// 16 rows/wave doubled B-side L2 traffic and refunded the barrier-removal win).
__device__ __forceinline__ void bload_mfma2(const short* __restrict__ bh,
                                            short8 ahi0, short8 alo0,
                                            short8 ahi1, short8 alo1,
                                            floatx4* acc0, floatx4* acc1) {
    short8 bhi[8], blo[8];
#pragma unroll
    for (int c = 0; c < 8; ++c) {
        bhi[c] = *(const short8*)(bh + c * 128);
        blo[c] = *(const short8*)(bh + 16384 + c * 128);
    }
#pragma unroll
    for (int c = 0; c < 8; ++c) {
        acc0[c] = __builtin_amdgcn_mfma_f32_16x16x32_bf16(ahi0, bhi[c], acc0[c], 0, 0, 0);
        acc0[c] = __builtin_amdgcn_mfma_f32_16x16x32_bf16(alo0, bhi[c], acc0[c], 0, 0, 0);
        acc0[c] = __builtin_amdgcn_mfma_f32_16x16x32_bf16(ahi0, blo[c], acc0[c], 0, 0, 0);
        acc1[c] = __builtin_amdgcn_mfma_f32_16x16x32_bf16(ahi1, bhi[c], acc1[c], 0, 0, 0);
        acc1[c] = __builtin_amdgcn_mfma_f32_16x16x32_bf16(alo1, bhi[c], acc1[c], 0, 0, 0);
        acc1[c] = __builtin_amdgcn_mfma_f32_16x16x32_bf16(ahi1, blo[c], acc1[c], 0, 0, 0);
    }
}

// VARIANT 0 (pre+conv0):  T = A@W1+b1 -> tbuf and fp32 OutG(H); OutC = fp16(T@W2)
// VARIANT 1 (FFN+conv):   T = relu(A@W1+b1) -> tbuf;
//                         Hn = LN(T@W2+b2+Res) -> tbuf and fp32 OutG(H);
//                         OutC = fp16(Hn@W3)
template <int VARIANT>
__device__ __forceinline__ void gemm_core(int tid, int bid,
                                          const float* __restrict__ A, const short* __restrict__ W1pk,
                                          const float* __restrict__ b1, const short* __restrict__ W2pk,
                                          const float* __restrict__ b2, const float* __restrict__ Res,
                                          const float* __restrict__ gamma, const float* __restrict__ beta,
                                          const short* __restrict__ W3pk,
                                          float* __restrict__ OutG, __half* __restrict__ OutC) {
    __shared__ float tbuf[64 * TSTRIDE];    // 33 KB wave-private rows (only LDS)
    const int lane = tid & 63;
    const int wv = tid >> 6;                 // 0..1
    const int row0 = bid * 64 + wv * 32;
    const int m = lane & 15;
    const int quad = lane >> 4;

    floatx4 acc[2][8];
#pragma unroll
    for (int t = 0; t < 2; ++t)
#pragma unroll
        for (int c = 0; c < 8; ++c) acc[t][c] = (floatx4){0.f, 0.f, 0.f, 0.f};

    const float* arow0 = A + (size_t)(row0 + m) * CH + quad * 8;
    const float* arow1 = arow0 + (size_t)16 * CH;
    float* trow_w = tbuf + (wv * 32) * TSTRIDE;             // epilogue writes
    const float* trow0 = tbuf + (wv * 32 + m) * TSTRIDE + quad * 8;  // A-frag reads
    const float* trow1 = trow0 + 16 * TSTRIDE;
    // per-lane B-fragment position inside a packed W plane:
    // hi addr = Wpk + kk*4096 + quad*1024 + m*8 + c*128 ; lo at +16384
    const int boff = quad * 1024 + m * 8;

    // ---------------- GEMM 1: A @ W1 ----------------
#pragma unroll 1
    for (int kk = 0; kk < 4; ++kk) {
        float4 a0 = *(const float4*)(arow0 + kk * 32);
        float4 a1 = *(const float4*)(arow0 + kk * 32 + 4);
        float4 a2 = *(const float4*)(arow1 + kk * 32);
        float4 a3 = *(const float4*)(arow1 + kk * 32 + 4);
        float av0[8] = {a0.x, a0.y, a0.z, a0.w, a1.x, a1.y, a1.z, a1.w};
        float av1[8] = {a2.x, a2.y, a2.z, a2.w, a3.x, a3.y, a3.z, a3.w};
        short8 ahi0, alo0, ahi1, alo1;
        split8(av0, ahi0, alo0);
        split8(av1, ahi1, alo1);
        bload_mfma2(W1pk + kk * 4096 + boff, ahi0, alo0, ahi1, alo1, acc[0], acc[1]);
    }

    // T epilogue -> tbuf (and H to global for VARIANT 0); wave-private
#pragma unroll
    for (int t = 0; t < 2; ++t)
#pragma unroll
    for (int c = 0; c < 8; ++c) {
        int col = c * 16 + m;
        float bv = b1[col];
#pragma unroll
        for (int r = 0; r < 4; ++r) {
            int lrow = t * 16 + quad * 4 + r;
            float v = acc[t][c][r] + bv;
            if (VARIANT == 1) v = fmaxf(v, 0.f);
            trow_w[lrow * TSTRIDE + col] = v;
            if (VARIANT == 0)
                OutG[(size_t)(row0 + lrow) * CH + col] = v;
        }
        acc[t][c] = (floatx4){0.f, 0.f, 0.f, 0.f};
    }
    lds_fence();   // cross-lane tbuf handoff: writes above, reads below

    // ---------------- GEMM 2: T @ W2 ----------------
#pragma unroll 1
    for (int kk = 0; kk < 4; ++kk) {
        float av0[8], av1[8];
#pragma unroll
        for (int j = 0; j < 8; ++j) av0[j] = trow0[kk * 32 + j];
#pragma unroll
        for (int j = 0; j < 8; ++j) av1[j] = trow1[kk * 32 + j];
        short8 ahi0, alo0, ahi1, alo1;
        split8(av0, ahi0, alo0);
        split8(av1, ahi1, alo1);
        bload_mfma2(W2pk + kk * 4096 + boff, ahi0, alo0, ahi1, alo1, acc[0], acc[1]);
    }

    if (VARIANT == 0) {
        // conv0 out: plain acc -> fp16 (conv bias applied in agg)
#pragma unroll
        for (int t = 0; t < 2; ++t)
#pragma unroll
        for (int c = 0; c < 8; ++c) {
            int col = c * 16 + m;
#pragma unroll
            for (int r = 0; r < 4; ++r) {
                int row = row0 + t * 16 + quad * 4 + r;
                OutC[(size_t)row * CH + col] = __float2half(acc[t][c][r]);
            }
        }
        return;
    }

    // ---------------- FFN epilogue: LN(acc + b2 + Res) ----------------
#pragma unroll
    for (int t = 0; t < 2; ++t)
#pragma unroll
    for (int c = 0; c < 8; ++c) {
        int col = c * 16 + m;
        float bv = b2[col];
#pragma unroll
        for (int r = 0; r < 4; ++r)
            acc[t][c][r] += bv + Res[(size_t)(row0 + t * 16 + quad * 4 + r) * CH + col];
    }
#pragma unroll
    for (int t = 0; t < 2; ++t)
#pragma unroll
    for (int r = 0; r < 4; ++r) {
        float s = 0.f, q = 0.f;
#pragma unroll
        for (int c = 0; c < 8; ++c) {
            float v = acc[t][c][r];
            s += v;
            q = fmaf(v, v, q);
        }
#pragma unroll
        for (int msk = 1; msk < 16; msk <<= 1) {
            s += __shfl_xor(s, msk);
            q += __shfl_xor(q, msk);
        }
        float mean = s * (1.f / CH);
        float var = q * (1.f / CH) - mean * mean;
        float rstd = rsqrtf(var + LN_EPS);
        int lrow = t * 16 + quad * 4 + r;
        int row = row0 + lrow;
#pragma unroll
        for (int c = 0; c < 8; ++c) {
            int col = c * 16 + m;
            float y = (acc[t][c][r] - mean) * rstd * gamma[col] + beta[col];
            OutG[(size_t)row * CH + col] = y;
            trow_w[lrow * TSTRIDE + col] = y;   // wave-private rows
        }
    }
#pragma unroll
    for (int t = 0; t < 2; ++t)
#pragma unroll
    for (int c = 0; c < 8; ++c) acc[t][c] = (floatx4){0.f, 0.f, 0.f, 0.f};
    lds_fence();   // cross-lane tbuf handoff: writes above, reads below

    // ---------------- GEMM 3: Hn @ W3 (next layer's conv) ----------------
#pragma unroll 1
    for (int kk = 0; kk < 4; ++kk) {
        float av0[8], av1[8];
#pragma unroll
        for (int j = 0; j < 8; ++j) av0[j] = trow0[kk * 32 + j];
#pragma unroll
        for (int j = 0; j < 8; ++j) av1[j] = trow1[kk * 32 + j];
        short8 ahi0, alo0, ahi1, alo1;
        split8(av0, ahi0, alo0);
        split8(av1, ahi1, alo1);
        bload_mfma2(W3pk + kk * 4096 + boff, ahi0, alo0, ahi1, alo1, acc[0], acc[1]);
    }

#pragma unroll
    for (int t = 0; t < 2; ++t)
#pragma unroll
    for (int c = 0; c < 8; ++c) {
        int col = c * 16 + m;
#pragma unroll
        for (int r = 0; r < 4; ++r) {
            int row = row0 + t * 16 + quad * 4 + r;
            OutC[(size_t)row * CH + col] = __float2half(acc[t][c][r]);
        }
    }
}

// variant-1 standalone kernel (FFN+conv triple-fusion) — 128 THREADS ONLY
template <int VARIANT>
__launch_bounds__(128, 2)
__global__ void gemm_fused(const float* __restrict__ A, const short* __restrict__ W1pk,
                           const float* __restrict__ b1, const short* __restrict__ W2pk,
                           const float* __restrict__ b2, const float* __restrict__ Res,
                           const float* __restrict__ gamma, const float* __restrict__ beta,
                           const short* __restrict__ W3pk,
                           float* __restrict__ OutG, __half* __restrict__ OutC) {
    gemm_core<VARIANT>(threadIdx.x, blockIdx.x, A, W1pk, b1, W2pk, b2, Res,
                       gamma, beta, W3pk, OutG, OutC);
}

// Co-launch: blocks [0,GBLK) = variant-0 gemm (pre-scaler + conv0; threads
// 128..255 exit immediately — zero barriers in gemm path); blocks
// [GBLK,GBLK+FBLK) = fill_csr hiding under the gemm latency shadow
// (R6: fill added only ~5 us to the gemm0 dispatch).
__launch_bounds__(256, 2)
__global__ void fillgemm0_kernel(const int* __restrict__ ei, const int* __restrict__ rowptr,
                                 int* __restrict__ fill, int* __restrict__ srcs,
                                 const float* __restrict__ A, const short* __restrict__ W1pk,
                                 const float* __restrict__ b1, const short* __restrict__ W2pk,
                                 float* __restrict__ OutG, __half* __restrict__ OutC) {
    int bid = blockIdx.x;
    if (bid < GBLK) {
        if (threadIdx.x >= 128) return;
        gemm_core<0>(threadIdx.x, bid, A, W1pk, b1, W2pk, nullptr, nullptr,
                     nullptr, nullptr, nullptr, OutG, OutC);
        return;
    }
    int e = (bid - GBLK) * 256 + threadIdx.x;
    int s = ei[e];
    int d = ei[N_EDGES + e];
    int pos = atomicAdd(&fill[d], 1);
    srcs[rowptr[d] + pos] = s;
}

// ---------------------------------------------------------------- aggregation
// R12: TWO nodes per wave (32 lanes each), half4 (8B) gathers. Per j-step one
// load instruction serves 2 edges -> ~30% fewer wave-instructions/edge than
// the 1-node/wave half2 version. BIT-IDENTICAL by construction:
//  - per channel c (component c&3 of lane c>>2) fma retirement is strictly
//    edge-ascending, same as before (R5/R8/R9: j-order is numerics-pinned);
//  - LN tree congruent: old 64-lane butterfly level-0 (xor 1) == new
//    intra-lane (h0+h1)+(h2+h3) (IEEE add commutative -> old even/odd lanes
//    held bitwise-equal values); old levels 1..5 == new xor 1..16 over 32.
// FUSED=1: Hres = relu(LN(agg+bias)) + Hres.  FUSED=0: Out = agg+bias.
// (R15 lesson: do NOT fuse pooling via direct atomics.)
template <int FUSED>
__launch_bounds__(256)
__global__ void agg_kernel(const __half* __restrict__ HW, const int* __restrict__ rowptr,
                           const int* __restrict__ srcs, const float* __restrict__ isq,
                           const float* __restrict__ bias, const float* __restrict__ gamma,
                           const float* __restrict__ beta, float* __restrict__ Hres,
                           float* __restrict__ Out) {
    const int sub = threadIdx.x & 31;                    // lane within half-wave
    const int node = blockIdx.x * 8 + (threadIdx.x >> 5);
    const int start = rowptr[node];
    const int end = rowptr[node + 1];

    float a0 = 0.f, a1 = 0.f, a2 = 0.f, a3 = 0.f;
    for (int base = start; base < end; base += 32) {
        int idx = base + sub;
        int clamped = (idx < end) ? idx : (end - 1);
        int sl = srcs[clamped];
        float wl = isq[sl];
        int cnt = end - base;
        if (cnt > 32) cnt = 32;
        int j = 0;
        for (; j + 8 <= cnt; j += 8) {
            int s[8];
            float w[8];
            float2 pk[8];
#pragma unroll
            for (int q = 0; q < 8; ++q) {
                s[q] = __shfl(sl, j + q, 32);
                w[q] = __shfl(wl, j + q, 32);
            }
#pragma unroll
            for (int q = 0; q < 8; ++q)
                pk[q] = *(const float2*)(HW + (size_t)s[q] * CH + sub * 4);
#pragma unroll
            for (int q = 0; q < 8; ++q) {
                float2 fa = __half22float2(*(const __half2*)&pk[q].x);
                float2 fb = __half22float2(*(const __half2*)&pk[q].y);
                a0 = fmaf(w[q], fa.x, a0);
                a1 = fmaf(w[q], fa.y, a1);
                a2 = fmaf(w[q], fb.x, a2);
                a3 = fmaf(w[q], fb.y, a3);
            }
        }
        for (; j + 4 <= cnt; j += 4) {
            int s0 = __shfl(sl, j, 32), s1 = __shfl(sl, j + 1, 32);
            int s2 = __shfl(sl, j + 2, 32), s3 = __shfl(sl, j + 3, 32);
            float w0 = __shfl(wl, j, 32), w1 = __shfl(wl, j + 1, 32);
            float w2 = __shfl(wl, j + 2, 32), w3 = __shfl(wl, j + 3, 32);
            float2 p0 = *(const float2*)(HW + (size_t)s0 * CH + sub * 4);
            float2 p1 = *(const float2*)(HW + (size_t)s1 * CH + sub * 4);
            float2 p2 = *(const float2*)(HW + (size_t)s2 * CH + sub * 4);
            float2 p3 = *(const float2*)(HW + (size_t)s3 * CH + sub * 4);
            {
                float2 fa = __half22float2(*(const __half2*)&p0.x);
                float2 fb = __half22float2(*(const __half2*)&p0.y);
                a0 = fmaf(w0, fa.x, a0); a1 = fmaf(w0, fa.y, a1);
                a2 = fmaf(w0, fb.x, a2); a3 = fmaf(w0, fb.y, a3);
            }
            {
                float2 fa = __half22float2(*(const __half2*)&p1.x);
                float2 fb = __half22float2(*(const __half2*)&p1.y);
                a0 = fmaf(w1, fa.x, a0); a1 = fmaf(w1, fa.y, a1);
                a2 = fmaf(w1, fb.x, a2); a3 = fmaf(w1, fb.y, a3);
            }
            {
                float2 fa = __half22float2(*(const __half2*)&p2.x);
                float2 fb = __half22float2(*(const __half2*)&p2.y);
                a0 = fmaf(w2, fa.x, a0); a1 = fmaf(w2, fa.y, a1);
                a2 = fmaf(w2, fb.x, a2); a3 = fmaf(w2, fb.y, a3);
            }
            {
                float2 fa = __half22float2(*(const __half2*)&p3.x);
                float2 fb = __half22float2(*(const __half2*)&p3.y);
                a0 = fmaf(w3, fa.x, a0); a1 = fmaf(w3, fa.y, a1);
                a2 = fmaf(w3, fb.x, a2); a3 = fmaf(w3, fb.y, a3);
            }
        }
        for (; j < cnt; ++j) {
            int s = __shfl(sl, j, 32);
            float w = __shfl(wl, j, 32);
            float2 p = *(const float2*)(HW + (size_t)s * CH + sub * 4);
            float2 fa = __half22float2(*(const __half2*)&p.x);
            float2 fb = __half22float2(*(const __half2*)&p.y);
            a0 = fmaf(w, fa.x, a0); a1 = fmaf(w, fa.y, a1);
            a2 = fmaf(w, fb.x, a2); a3 = fmaf(w, fb.y, a3);
        }
    }
    float d = isq[node];
    float2 hp4 = *(const float2*)(HW + (size_t)node * CH + sub * 4);
    float2 ha = __half22float2(*(const __half2*)&hp4.x);
    float2 hb = __half22float2(*(const __half2*)&hp4.y);
    const float4 bb = *(const float4*)(bias + sub * 4);
    float h0 = d * a0 + d * d * ha.x + bb.x;
    float h1 = d * a1 + d * d * ha.y + bb.y;
    float h2 = d * a2 + d * d * hb.x + bb.z;
    float h3 = d * a3 + d * d * hb.y + bb.w;

    if (!FUSED) {
        float4 o;
        o.x = h0; o.y = h1; o.z = h2; o.w = h3;
        *(float4*)(Out + (size_t)node * CH + sub * 4) = o;
        return;
    }
    // LN reduction: intra-lane (h0+h1)+(h2+h3) replicates old xor-1 level
    // (commutative adds -> old lane pair held bitwise-equal values), then
    // xor 1..16 over the 32-lane half == old xor 2..32. Bit-identical.
    float sum = (h0 + h1) + (h2 + h3);
    float sq = (h0 * h0 + h1 * h1) + (h2 * h2 + h3 * h3);
    for (int msk = 1; msk < 32; msk <<= 1) {
        sum += __shfl_xor(sum, msk);
        sq += __shfl_xor(sq, msk);
    }
    float mean = sum * (1.f / CH);
    float var = sq * (1.f / CH) - mean * mean;
    float rstd = rsqrtf(var + LN_EPS);
    const float4 gg = *(const float4*)(gamma + sub * 4);
    const float4 be = *(const float4*)(beta + sub * 4);
    float y0 = (h0 - mean) * rstd * gg.x + be.x;
    float y1 = (h1 - mean) * rstd * gg.y + be.y;
    float y2 = (h2 - mean) * rstd * gg.z + be.z;
    float y3 = (h3 - mean) * rstd * gg.w + be.w;
    float4* hp = (float4*)(Hres + (size_t)node * CH + sub * 4);
    float4 rr = *hp;
    float4 o;
    o.x = fmaxf(y0, 0.f) + rr.x;
    o.y = fmaxf(y1, 0.f) + rr.y;
    o.z = fmaxf(y2, 0.f) + rr.z;
    o.w = fmaxf(y3, 0.f) + rr.w;
    *hp = o;
}

// ---------------------------------------------------------------- pooling
__launch_bounds__(256)
__global__ void pool_kernel(const float* __restrict__ H, const int* __restrict__ batch,
                            float* __restrict__ g, float* __restrict__ cntf) {
    const int lane = threadIdx.x & 63;
    const int w = blockIdx.x * 4 + (threadIdx.x >> 6);
    const int n0 = w * 16;
    float lx = 0.f, ly = 0.f;
    int run = 0;
    int cur = batch[n0];
    for (int t = 0; t < 16; ++t) {
        int n = n0 + t;
        int b = batch[n];
        if (b != cur) {
            atomicAdd(&g[(size_t)cur * CH + lane * 2], lx);
            atomicAdd(&g[(size_t)cur * CH + lane * 2 + 1], ly);
            if (lane == 0) atomicAdd(&cntf[cur], (float)run);
            lx = ly = 0.f; run = 0; cur = b;
        }
        const float2 v = *(const float2*)(H + (size_t)n * CH + lane * 2);
        lx += v.x; ly += v.y; ++run;
    }
    atomicAdd(&g[(size_t)cur * CH + lane * 2], lx);
    atomicAdd(&g[(size_t)cur * CH + lane * 2 + 1], ly);
    if (lane == 0) atomicAdd(&cntf[cur], (float)run);
}

// ---------------------------------------------------------------- classifier
__launch_bounds__(128)
__global__ void cls_kernel(const float* __restrict__ g, const float* __restrict__ cntf,
                           const float* __restrict__ w1, const float* __restrict__ b1,
                           const float* __restrict__ w2, const float* __restrict__ b2,
                           float* __restrict__ out) {
    __shared__ float gm[CH];
    __shared__ float red[2];
    const int b = blockIdx.x;
    const int t = threadIdx.x;
    float inv = 1.f / fmaxf(cntf[b], 1.f);
    gm[t] = g[(size_t)b * CH + t] * inv;
    __syncthreads();
    float acc = b1[t];
    for (int k = 0; k < CH; ++k) acc = fmaf(gm[k], w1[(size_t)k * CH + t], acc);
    float v = fmaxf(acc, 0.f) * w2[t];
    for (int msk = 1; msk < 64; msk <<= 1) v += __shfl_xor(v, msk);
    if ((t & 63) == 0) red[t >> 6] = v;
    __syncthreads();
    if (t == 0) out[b] = red[0] + red[1] + b2[0];
}

// ---------------------------------------------------------------- launch

extern "C" void kernel_launch(void* const* d_in, const int* in_sizes, int n_in,
                              void* d_out, int out_size, void* d_ws, size_t ws_size,
                              hipStream_t stream) {
    const float* x      = (const float*)d_in[0];
    const int*   ei     = (const int*)d_in[1];
    const int*   batch  = (const int*)d_in[2];
    const float* pre_w  = (const float*)d_in[3];
    const float* pre_b  = (const float*)d_in[4];
    const float* conv_w = (const float*)d_in[5];
    const float* conv_b = (const float*)d_in[6];
    const float* ln_g   = (const float*)d_in[7];
    const float* ln_b   = (const float*)d_in[8];
    const float* ffn_w1 = (const float*)d_in[9];
    const float* ffn_b1 = (const float*)d_in[10];
    const float* ffn_w2 = (const float*)d_in[11];
    const float* ffn_b2 = (const float*)d_in[12];
    const float* fln_g  = (const float*)d_in[13];
    const float* fln_b  = (const float*)d_in[14];
    const float* cls_w1 = (const float*)d_in[15];
    const float* cls_b1 = (const float*)d_in[16];
    const float* cls_w2 = (const float*)d_in[17];
    const float* cls_b2 = (const float*)d_in[18];

    float* H    = (float*)d_ws;                       // 40000*128 f32 (residual)
    float* T    = H + (size_t)N_NODES * CH;           // f32 (final agg out)
    float* R    = T + (size_t)N_NODES * CH;           // scratch
    __half* HWh = (__half*)R;                         // conv out fp16 (alias)
    int*   degi = (int*)(R + (size_t)N_NODES * CH);
    int*   fill = degi + N_NODES;
    float* g    = (float*)(fill + N_NODES);           // zero zone contiguous
    float* cntf = g + (size_t)NB * CH;
    float* isq  = cntf + NB;
    int*  rowptr = (int*)(isq + N_NODES);
    int*  bsum   = rowptr + N_NODES + 1;
    int*  boff   = bsum + 256;
    int*  srcs   = boff + 256;
    short* wpk   = (short*)(srcs + N_EDGES);          // 8 x 32768 shorts

    const int nb_scan = (N_NODES + 255) / 256;  // 157

    hipMemsetAsync(degi, 0, (size_t)(2 * N_NODES + NB * CH + NB) * sizeof(int), stream);

    // deg (atomics) + W pack co-launched (independent)
    degpack_kernel<<<FBLK + 512, 256, 0, stream>>>(ei, degi, pre_w, conv_w,
                                                   ffn_w1, ffn_w2, wpk);
    scan1_kernel<<<nb_scan, 256, 0, stream>>>(degi, rowptr, bsum, isq);
    scan23_kernel<<<nb_scan, 256, 0, stream>>>(bsum, rowptr, nb_scan);
    // fill_csr + (pre-scaler + conv0 gemm) co-launched (independent)
    fillgemm0_kernel<<<GBLK + FBLK, 256, 0, stream>>>(ei, rowptr, fill, srcs,
                                                      x, wpk, pre_b,
                                                      wpk + 1 * 32768, H, HWh);

    const int ablk = N_NODES / 8;    // 5000 (2 nodes/wave, 8 nodes/block)

    for (int i = 0; i < NL; ++i) {
        if (i < NL - 1) {
            // H = relu(LN(agg(HWh)+conv_b)) + H   (fused)
            agg_kernel<1><<<ablk, 256, 0, stream>>>(HWh, rowptr, srcs, isq,
                                                    conv_b + (size_t)i * CH,
                                                    ln_g + (size_t)i * CH,
                                                    ln_b + (size_t)i * CH, H, nullptr);
            // H = LN(relu(H@w1+b1)@w2+b2+H); HWh = fp16(H@conv_w[i+1])  (triple-fused)
            gemm_fused<1><<<GBLK, 128, 0, stream>>>(H, wpk + (size_t)(4 + i) * 32768,
                                                    ffn_b1 + (size_t)i * CH,
                                                    wpk + (size_t)(6 + i) * 32768,
                                                    ffn_b2 + (size_t)i * CH, H,
                                                    fln_g + (size_t)i * CH,
                                                    fln_b + (size_t)i * CH,
                                                    wpk + (size_t)(2 + i) * 32768,
                                                    H, HWh);
        } else {
            // T = agg(HWh) + conv_b   (fp32)
            agg_kernel<0><<<ablk, 256, 0, stream>>>(HWh, rowptr, srcs, isq,
                                                    conv_b + (size_t)i * CH,
                                                    nullptr, nullptr, nullptr, T);
        }
    }

    pool_kernel<<<N_NODES / 64, 256, 0, stream>>>(T, batch, g, cntf);
    cls_kernel<<<NB, CH, 0, stream>>>(g, cntf, cls_w1, cls_b1, cls_w2, cls_b2,
                                      (float*)d_out);
}